// Round 7
// baseline (2849.654 us; speedup 1.0000x reference)
//
#include <hip/hip_runtime.h>

#define NN 50000
#define NE 200000
#define DD 128
#define GG 256
#define NITERS 2
#define NBINS 50176          // 196 * 256, >= NN
#define NPART 196

typedef unsigned short u16;
typedef unsigned int u32;
typedef __bf16 bf16x8 __attribute__((ext_vector_type(8)));
typedef float f32x4 __attribute__((ext_vector_type(4)));

union U16x8 { uint4 u; bf16x8 v; u16 s[8]; };

__device__ __forceinline__ u16 f2b(float f) {             // f32 -> bf16 bits, RNE
    u32 u = __float_as_uint(f);
    return (u16)((u + 0x7FFFu + ((u >> 16) & 1u)) >> 16);
}
__device__ __forceinline__ float b2f(u16 s) { return __uint_as_float(((u32)s) << 16); }

__device__ __forceinline__ uint2 pack4(const float* v) {
    uint2 r;
    r.x = (u32)f2b(v[0]) | ((u32)f2b(v[1]) << 16);
    r.y = (u32)f2b(v[2]) | ((u32)f2b(v[3]) << 16);
    return r;
}

// async global -> LDS, 16B per lane; lds must be the wave-uniform base slot
__device__ __forceinline__ void gload_lds16(const void* g, void* lds) {
    __builtin_amdgcn_global_load_lds((const __attribute__((address_space(1))) void*)g,
                                     (__attribute__((address_space(3))) void*)lds, 16, 0, 0);
}

// XCD-chunked bijective block swizzle (m204 form)
__device__ __forceinline__ int xcd_swz(int orig, int nwg) {
    int q = nwg >> 3, r = nwg & 7;
    int x = orig & 7, loc = orig >> 3;
    return (x < r ? x * (q + 1) : r * (q + 1) + (x - r) * q) + loc;
}

// ---------------------------------------------------------------------------
// expand_k: OUT[128 rows][NL*128 cols] = epi(A[128][K] @ W + bias)
// A (bf16, row-major, stride K) staged ONCE in LDS (K*256 B); W fragments
// per-lane direct global loads (L2-hot); swapped-operand MFMA so each thread
// owns 4 consecutive out-cols of one row -> direct vector stores, no bounce,
// exactly one __syncthreads in the kernel.
// EPI: 0 = bf16 store (ob, ldN=LDN); 1 = f32 of + bf16 ob (LDN=128);
//      2 = residual: of += , ob mirror (LDN=128).
// ---------------------------------------------------------------------------
template<int K, int NL, int EPI, bool RELU, int LDN>
__global__ __launch_bounds__(256) void expand_k(
    const u16* __restrict__ A, const uint4* __restrict__ wfrag,
    const float* __restrict__ bias, float* __restrict__ of, u16* __restrict__ ob,
    int M)
{
    constexpr int KS = K / 32;
    __shared__ uint4 smem[K * 16];     // 32 KB (K=128) / 64 KB (K=256)
    const int t = threadIdx.x, l = t & 63, wv = t >> 6;
    const int mh = wv >> 1, nh = wv & 1;
    const int mblk = blockIdx.x;

    #pragma unroll
    for (int i = 0; i < K / 16; ++i) {           // stage A once
        int s = t + 256 * i;
        int ln = s & 63, mt = (s >> 6) & 7, ksl = s >> 9;
        int row = mblk * 128 + mt * 16 + (ln & 15);
        if (row >= M) row = M - 1;
        int kk = ksl * 32 + (ln >> 4) * 8;
        gload_lds16(A + (size_t)row * K + kk, &smem[s - ln]);
    }
    __syncthreads();

    for (int c = 0; c < NL; ++c) {
        f32x4 acc[4][4] = {};
        #pragma unroll
        for (int ksl = 0; ksl < KS; ++ksl) {
            uint4 wa[4];
            #pragma unroll
            for (int mi = 0; mi < 4; ++mi)
                wa[mi] = wfrag[(size_t)((c * KS + ksl) * 8 + mh * 4 + mi) * 64 + l];
            bf16x8 bn[4];
            #pragma unroll
            for (int ni = 0; ni < 4; ++ni) { U16x8 u; u.u = smem[(ksl * 8 + nh * 4 + ni) * 64 + l]; bn[ni] = u.v; }
            #pragma unroll
            for (int mi = 0; mi < 4; ++mi) {
                U16x8 u; u.u = wa[mi];
                #pragma unroll
                for (int ni = 0; ni < 4; ++ni)
                    acc[mi][ni] = __builtin_amdgcn_mfma_f32_16x16x32_bf16(u.v, bn[ni], acc[mi][ni], 0, 0, 0);
            }
        }
        // epilogue: thread (l), frag (mi,ni), reg r ->
        //   row  = mblk*128 + nh*64 + ni*16 + (l&15)
        //   col  = c*128 + mh*64 + mi*16 + 4*(l>>4) + r   (4 consecutive)
        float4 bb[4];
        #pragma unroll
        for (int mi = 0; mi < 4; ++mi) {
            if (bias) bb[mi] = *(const float4*)(bias + c * 128 + mh * 64 + mi * 16 + 4 * (l >> 4));
            else { bb[mi].x = 0.f; bb[mi].y = 0.f; bb[mi].z = 0.f; bb[mi].w = 0.f; }
        }
        #pragma unroll
        for (int ni = 0; ni < 4; ++ni) {
            int node = mblk * 128 + nh * 64 + ni * 16 + (l & 15);
            if (node >= M) continue;
            #pragma unroll
            for (int mi = 0; mi < 4; ++mi) {
                int col = c * 128 + mh * 64 + mi * 16 + 4 * (l >> 4);
                float v[4];
                const float* bf = &bb[mi].x;
                #pragma unroll
                for (int r = 0; r < 4; ++r) {
                    v[r] = acc[mi][ni][r] + bf[r];
                    if (RELU) v[r] = fmaxf(v[r], 0.f);
                }
                if (EPI == 0) {
                    *(uint2*)(ob + (size_t)node * LDN + col) = pack4(v);
                } else {
                    size_t a = (size_t)node * 128 + col;
                    if (EPI == 2) {
                        float4 old = *(const float4*)(of + a);
                        v[0] += old.x; v[1] += old.y; v[2] += old.z; v[3] += old.w;
                    }
                    float4 s4; s4.x = v[0]; s4.y = v[1]; s4.z = v[2]; s4.w = v[3];
                    *(float4*)(of + a) = s4;
                    *(uint2*)(ob + a) = pack4(v);
                }
            }
        }
    }
}

// ---------------------------------------------------------------------------
// outhead_k: per 64-node tile, h = relu(Hout1[64][512] @ Wo2 + bo2) [64][1024]
// then segment-max by batch_vec into out[256][1024] (sorted runs ni-merged,
// uint atomicMax; out zero-inited, relu >= 0). A staged once (64 KB).
// ---------------------------------------------------------------------------
__global__ __launch_bounds__(256) void outhead_k(
    const u16* __restrict__ A, const uint4* __restrict__ wfrag,
    const float* __restrict__ bias, const int* __restrict__ bvec,
    float* __restrict__ gout, int M)
{
    __shared__ uint4 smem[4096];       // 64 rows x 512 cols bf16 = 64 KB
    __shared__ int sb[64];
    const int t = threadIdx.x, l = t & 63, wv = t >> 6;
    const int mh = wv >> 1, nh = wv & 1;
    const int mblk = blockIdx.x;

    if (t < 64) sb[t] = bvec[min(mblk * 64 + t, M - 1)];

    #pragma unroll
    for (int i = 0; i < 16; ++i) {               // stage A once: [ksl16][mt4][64]
        int s = t + 256 * i;
        int ln = s & 63, mt = (s >> 6) & 3, ksl = s >> 8;
        int row = mblk * 64 + mt * 16 + (ln & 15);
        if (row >= M) row = M - 1;
        int kk = ksl * 32 + (ln >> 4) * 8;
        gload_lds16(A + (size_t)row * 512 + kk, &smem[s - ln]);
    }
    __syncthreads();

    #pragma unroll 1
    for (int c = 0; c < 8; ++c) {
        f32x4 acc[4][2] = {};
        #pragma unroll
        for (int ksl = 0; ksl < 16; ++ksl) {
            uint4 wa[4];
            #pragma unroll
            for (int mi = 0; mi < 4; ++mi)
                wa[mi] = wfrag[(size_t)((c * 16 + ksl) * 8 + mh * 4 + mi) * 64 + l];
            bf16x8 bn[2];
            #pragma unroll
            for (int ni = 0; ni < 2; ++ni) { U16x8 u; u.u = smem[(ksl * 4 + nh * 2 + ni) * 64 + l]; bn[ni] = u.v; }
            #pragma unroll
            for (int mi = 0; mi < 4; ++mi) {
                U16x8 u; u.u = wa[mi];
                #pragma unroll
                for (int ni = 0; ni < 2; ++ni)
                    acc[mi][ni] = __builtin_amdgcn_mfma_f32_16x16x32_bf16(u.v, bn[ni], acc[mi][ni], 0, 0, 0);
            }
        }
        #pragma unroll
        for (int mi = 0; mi < 4; ++mi) {
            int col = c * 128 + mh * 64 + mi * 16 + 4 * (l >> 4);
            float4 bb = *(const float4*)(bias + col);
            const float* bf = &bb.x;
            float mv[4]; int cg = -1;
            #pragma unroll
            for (int ni = 0; ni < 2; ++ni) {
                int b = sb[nh * 32 + ni * 16 + (l & 15)];   // clamped rows dup M-1: safe
                float v[4];
                #pragma unroll
                for (int r = 0; r < 4; ++r)
                    v[r] = fmaxf(acc[mi][ni][r] + bf[r], 0.f);
                if (b != cg) {
                    if (cg >= 0) {
                        #pragma unroll
                        for (int r = 0; r < 4; ++r)
                            atomicMax((u32*)(gout + (size_t)cg * 1024 + col + r), __float_as_uint(mv[r]));
                    }
                    cg = b;
                    #pragma unroll
                    for (int r = 0; r < 4; ++r) mv[r] = v[r];
                } else {
                    #pragma unroll
                    for (int r = 0; r < 4; ++r) mv[r] = fmaxf(mv[r], v[r]);
                }
            }
            if (cg >= 0) {
                #pragma unroll
                for (int r = 0; r < 4; ++r)
                    atomicMax((u32*)(gout + (size_t)cg * 1024 + col + r), __float_as_uint(mv[r]));
            }
        }
    }
}

// ---------------------------------------------------------------------------
// Source functors for computed A-operand staging (gemm_k).
// ---------------------------------------------------------------------------
struct SrcEnc {             // node encoder input: emb_node[x[row]] (f32 -> bf16)
    static constexpr bool DIRECT = false;
    const float* emb; const int* xids;
    __device__ const void* gaddr(int, int) const { return nullptr; }
    __device__ bf16x8 operator()(int row, int kk) const {
        int n = xids[row];
        const float* p = emb + (size_t)n * 256 + kk;
        float4 f0 = *(const float4*)p, f1 = *(const float4*)(p + 4);
        U16x8 r;
        r.s[0]=f2b(f0.x); r.s[1]=f2b(f0.y); r.s[2]=f2b(f0.z); r.s[3]=f2b(f0.w);
        r.s[4]=f2b(f1.x); r.s[5]=f2b(f1.y); r.s[6]=f2b(f1.z); r.s[7]=f2b(f1.w);
        return r.v;
    }
};
struct SrcUpd {             // [nodes | deg_inv*fi | deg_inv*fo] (f32 -> bf16), K=384
    static constexpr bool DIRECT = false;
    const float* nodes; const float* fi; const float* fo; const float* deg;
    __device__ const void* gaddr(int, int) const { return nullptr; }
    __device__ bf16x8 operator()(int row, int kk) const {
        const float* s; float sc = 1.f;
        if (kk < 128) s = nodes + (size_t)row * 128 + kk;
        else {
            float d = deg[row];
            sc = d > 0.f ? 1.f / d : 0.f;
            s = (kk < 256) ? fi + (size_t)row * 128 + (kk - 128)
                           : fo + (size_t)row * 128 + (kk - 256);
        }
        float4 f0 = *(const float4*)s, f1 = *(const float4*)(s + 4);
        U16x8 r;
        r.s[0]=f2b(f0.x*sc); r.s[1]=f2b(f0.y*sc); r.s[2]=f2b(f0.z*sc); r.s[3]=f2b(f0.w*sc);
        r.s[4]=f2b(f1.x*sc); r.s[5]=f2b(f1.y*sc); r.s[6]=f2b(f1.z*sc); r.s[7]=f2b(f1.w*sc);
        return r.v;
    }
};

struct EpiArgs { float* of; u16* ob; const int* idx; int ldN; };

// ---------------------------------------------------------------------------
// gemm_k (kept only for computed-staging layers: SrcEnc K=256, SrcUpd K=384).
// EPI0: bf16 store via swizzled LDS bounce.
// ---------------------------------------------------------------------------
template<int KDIM, int NBLK, int EPI, bool RELU, class SRC>
__global__ __launch_bounds__(256) void gemm_k(SRC src, const uint4* __restrict__ wfrag,
                                              const float* __restrict__ bias,
                                              EpiArgs ea, int M)
{
    constexpr int KS = KDIM / 32;
    constexpr int NPANEL = KDIM / 64;
    __shared__ uint4 smem[2048];
    const int t = threadIdx.x;
    const int l = t & 63;
    const int wv = t >> 6;
    const int mh = wv >> 1, nh = wv & 1;
    const int ell = xcd_swz(blockIdx.x, gridDim.x);
    const int mblk = ell / NBLK, nblk = ell % NBLK;

    f32x4 acc[4][4] = {};

    for (int p = 0; p < NPANEL; ++p) {
        __syncthreads();
        #pragma unroll
        for (int i = 0; i < 4; ++i) {              // computed A panel
            int s = t + 256 * i;
            int ln = s & 63, mt = (s >> 6) & 7, ksl = s >> 9;
            int row = mblk * 128 + mt * 16 + (ln & 15);
            if (row >= M) row = M - 1;
            int kk = p * 64 + ksl * 32 + (ln >> 4) * 8;
            U16x8 u; u.v = src(row, kk);
            smem[s] = u.u;
        }
        {                                           // async W panel
            const uint4* wp = wfrag + (size_t)(nblk * KS + 2 * p) * 512;
            #pragma unroll
            for (int i = 0; i < 4; ++i) {
                int s = t + 256 * i;
                gload_lds16(wp + s, &smem[1024 + (s - (s & 63))]);
            }
        }
        __syncthreads();
        #pragma unroll
        for (int ksl = 0; ksl < 2; ++ksl) {
            bf16x8 a[4], b[4];
            #pragma unroll
            for (int mi = 0; mi < 4; ++mi) { U16x8 u; u.u = smem[(ksl*8 + mh*4 + mi)*64 + l]; a[mi] = u.v; }
            #pragma unroll
            for (int ni = 0; ni < 4; ++ni) { U16x8 u; u.u = smem[1024 + (ksl*8 + nh*4 + ni)*64 + l]; b[ni] = u.v; }
            #pragma unroll
            for (int mi = 0; mi < 4; ++mi)
                #pragma unroll
                for (int ni = 0; ni < 4; ++ni)
                    acc[mi][ni] = __builtin_amdgcn_mfma_f32_16x16x32_bf16(a[mi], b[ni], acc[mi][ni], 0, 0, 0);
        }
    }

    float bcol[4];
    #pragma unroll
    for (int ni = 0; ni < 4; ++ni)
        bcol[ni] = bias ? bias[nblk * 128 + nh * 64 + ni * 16 + (l & 15)] : 0.f;

    // EPI0: bf16 store via XOR-swizzled LDS bounce
    __syncthreads();
    u16* bn = (u16*)smem;
    #pragma unroll
    for (int mi = 0; mi < 4; ++mi)
        #pragma unroll
        for (int ni = 0; ni < 4; ++ni)
            #pragma unroll
            for (int r = 0; r < 4; ++r) {
                int rl = mh * 64 + mi * 16 + (l >> 4) * 4 + r;
                int cl = nh * 64 + ni * 16 + (l & 15);
                float v = acc[mi][ni][r] + bcol[ni];
                if (RELU) v = fmaxf(v, 0.f);
                int sx = (rl >> 2) & 7;
                bn[rl * 128 + ((((cl >> 3) ^ sx)) << 3) + (cl & 7)] = f2b(v);
            }
    __syncthreads();
    int row = t >> 1, half = t & 1;
    int grow = mblk * 128 + row;
    if (grow < M) {
        int sx = (row >> 2) & 7;
        uint4* dst = (uint4*)(ea.ob + (size_t)grow * ea.ldN + nblk * 128 + half * 64);
        const uint4* sp = ((const uint4*)bn) + row * 16;
        #pragma unroll
        for (int i = 0; i < 8; ++i) dst[i] = sp[(half * 8 + i) ^ sx];
    }
}

// ---------------------------------------------------------------------------
// Fused per-edge pipeline (edges pre-sorted by idxA) — unchanged from R6.
// ---------------------------------------------------------------------------
__global__ __launch_bounds__(256) void edge_fused(
    const u16* __restrict__ P, const float* __restrict__ T,
    const uint4* __restrict__ W2f, const float* __restrict__ b2,
    const uint4* __restrict__ W3f, const float* __restrict__ b3,
    const int* __restrict__ idxA, const int* __restrict__ idxB,
    const int* __restrict__ eattr, float* __restrict__ agg)
{
    __shared__ uint4 smA[2048];
    __shared__ int   sidx[3][128];
    __shared__ float sT[768];
    const int t = threadIdx.x;
    const int l = t & 63;
    const int wv = t >> 6;
    const int mh = wv >> 1, nh = wv & 1;
    const int base = xcd_swz(blockIdx.x, gridDim.x) * 128;

    if (t < 128) {
        int e = (base + t < NE) ? base + t : NE - 1;
        sidx[0][t] = idxA[e];
        sidx[1][t] = idxB[e];
        sidx[2][t] = eattr[e];
    }
    for (int i = t; i < 768; i += 256) sT[i] = T[i];
    __syncthreads();

    const int rt0 = wv * 16 + (l & 15);
    const int rt1 = (wv + 4) * 16 + (l & 15);
    const int klo = (l >> 4) * 8;
    const u16* pA[2] = { P + (size_t)sidx[0][rt0] * 512, P + (size_t)sidx[0][rt1] * 512 };
    const u16* pB[2] = { P + (size_t)sidx[1][rt0] * 512 + 256, P + (size_t)sidx[1][rt1] * 512 + 256 };
    const float* pT[2] = { sT + sidx[2][rt0] * 256, sT + sidx[2][rt1] * 256 };

    uint4 ra[4], rb[4];
    #pragma unroll
    for (int i = 0; i < 4; ++i) {
        int kk = (i >> 1) * 32 + klo;
        ra[i] = *(const uint4*)(pA[i & 1] + kk);
        rb[i] = *(const uint4*)(pB[i & 1] + kk);
    }

    f32x4 acc[4][4] = {};
    #pragma unroll
    for (int p = 0; p < 4; ++p) {
        #pragma unroll
        for (int i = 0; i < 4; ++i) {
            int kk = (i >> 1) * 32 + klo;
            U16x8 ua, ub, r;
            ua.u = ra[i]; ub.u = rb[i];
            const float* tb = pT[i & 1] + p * 64 + kk;
            #pragma unroll
            for (int j = 0; j < 8; ++j) {
                float v = b2f(ua.s[j]) + b2f(ub.s[j]) + tb[j];
                r.s[j] = f2b(fmaxf(v, 0.f));
            }
            smA[(p & 1) * 1024 + t + 256 * i] = r.u;
            if (p < 3) {
                int kn = (p + 1) * 64 + kk;
                ra[i] = *(const uint4*)(pA[i & 1] + kn);
                rb[i] = *(const uint4*)(pB[i & 1] + kn);
            }
        }
        asm volatile("s_waitcnt lgkmcnt(0)" ::: "memory");
        __builtin_amdgcn_s_barrier();
        uint4 bw[2][4];
        #pragma unroll
        for (int ksl = 0; ksl < 2; ++ksl)
            #pragma unroll
            for (int ni = 0; ni < 4; ++ni)
                bw[ksl][ni] = W2f[(size_t)((p * 2 + ksl) * 8 + nh * 4 + ni) * 64 + l];
        #pragma unroll
        for (int ksl = 0; ksl < 2; ++ksl) {
            bf16x8 a[4];
            #pragma unroll
            for (int mi = 0; mi < 4; ++mi) { U16x8 u; u.u = smA[(p & 1) * 1024 + (ksl*8 + mh*4 + mi)*64 + l]; a[mi] = u.v; }
            #pragma unroll
            for (int mi = 0; mi < 4; ++mi)
                #pragma unroll
                for (int ni = 0; ni < 4; ++ni) {
                    U16x8 u; u.u = bw[ksl][ni];
                    acc[mi][ni] = __builtin_amdgcn_mfma_f32_16x16x32_bf16(a[mi], u.v, acc[mi][ni], 0, 0, 0);
                }
        }
    }

    float bc2[4];
    #pragma unroll
    for (int ni = 0; ni < 4; ++ni) bc2[ni] = b2[nh * 64 + ni * 16 + (l & 15)];
    __builtin_amdgcn_s_barrier();
    u16* bn = (u16*)smA;
    #pragma unroll
    for (int mi = 0; mi < 4; ++mi)
        #pragma unroll
        for (int ni = 0; ni < 4; ++ni)
            #pragma unroll
            for (int r = 0; r < 4; ++r) {
                int rl = mh * 64 + mi * 16 + (l >> 4) * 4 + r;
                int cl = nh * 64 + ni * 16 + (l & 15);
                float v = fmaxf(acc[mi][ni][r] + bc2[ni], 0.f);
                int sx = (rl >> 2) & 7;
                bn[rl * 128 + (((cl >> 3) ^ sx) << 3) + (cl & 7)] = f2b(v);
            }
    asm volatile("s_waitcnt lgkmcnt(0)" ::: "memory");
    __builtin_amdgcn_s_barrier();

    f32x4 acc2[4][4] = {};
    #pragma unroll
    for (int ks = 0; ks < 4; ++ks) {
        uint4 bw[4];
        #pragma unroll
        for (int ni = 0; ni < 4; ++ni)
            bw[ni] = W3f[(size_t)(ks * 8 + nh * 4 + ni) * 64 + l];
        bf16x8 a[4];
        #pragma unroll
        for (int mi = 0; mi < 4; ++mi) {
            int rl = (mh * 4 + mi) * 16 + (l & 15);
            int c0 = ks * 32 + (l >> 4) * 8;
            int sx = (rl >> 2) & 7;
            U16x8 u; u.u = *(const uint4*)&bn[rl * 128 + (((c0 >> 3) ^ sx) << 3)];
            a[mi] = u.v;
        }
        #pragma unroll
        for (int mi = 0; mi < 4; ++mi)
            #pragma unroll
            for (int ni = 0; ni < 4; ++ni) {
                U16x8 u; u.u = bw[ni];
                acc2[mi][ni] = __builtin_amdgcn_mfma_f32_16x16x32_bf16(a[mi], u.v, acc2[mi][ni], 0, 0, 0);
            }
    }

    float bc3[4];
    #pragma unroll
    for (int ni = 0; ni < 4; ++ni) bc3[ni] = b3[nh * 64 + ni * 16 + (l & 15)];
    #pragma unroll
    for (int mi = 0; mi < 4; ++mi) {
        int rt4 = mh * 64 + mi * 16 + (l >> 4) * 4;
        int nd[4];
        #pragma unroll
        for (int r = 0; r < 4; ++r)
            nd[r] = (base + rt4 + r < NE) ? sidx[0][rt4 + r] : -1;
        #pragma unroll
        for (int ni = 0; ni < 4; ++ni) {
            int col = nh * 64 + ni * 16 + (l & 15);
            float mv = 0.f; int cg = -1;
            #pragma unroll
            for (int r = 0; r < 4; ++r) {
                float v = fmaxf(acc2[mi][ni][r] + bc3[ni], 0.f);
                if (nd[r] != cg) {
                    if (cg >= 0) atomicAdd(agg + (size_t)cg * 128 + col, mv);
                    cg = nd[r]; mv = v;
                } else mv += v;
            }
            if (cg >= 0) atomicAdd(agg + (size_t)cg * 128 + col, mv);
        }
    }
}

// ---------------------------------------------------------------------------
// Counting sort of edges by key (dst or src), 50k bins.
// ---------------------------------------------------------------------------
__global__ void hist_kernel(const int* __restrict__ key, int* __restrict__ hist)
{
    int i = blockIdx.x * 256 + threadIdx.x;
    if (i < NE) atomicAdd(&hist[key[i]], 1);
}
__global__ void chunk_sum(const int* __restrict__ h, int* __restrict__ part)
{
    __shared__ int sh[256];
    int t = threadIdx.x, b = blockIdx.x;
    sh[t] = h[b * 256 + t];
    __syncthreads();
    for (int o = 128; o > 0; o >>= 1) { if (t < o) sh[t] += sh[t + o]; __syncthreads(); }
    if (t == 0) part[b] = sh[0];
}
__global__ void scan_part(int* part)
{
    __shared__ int sh[256];
    int t = threadIdx.x;
    sh[t] = (t < NPART) ? part[t] : 0;
    __syncthreads();
    for (int o = 1; o < 256; o <<= 1) {
        int x = (t >= o) ? sh[t - o] : 0;
        __syncthreads(); sh[t] += x; __syncthreads();
    }
    if (t < NPART) part[t] = t ? sh[t - 1] : 0;
}
__global__ void mk_cursor(const int* __restrict__ h, const int* __restrict__ part,
                          int* __restrict__ cur)
{
    __shared__ int sh[256];
    int t = threadIdx.x, b = blockIdx.x;
    int v = h[b * 256 + t];
    sh[t] = v;
    __syncthreads();
    for (int o = 1; o < 256; o <<= 1) {
        int x = (t >= o) ? sh[t - o] : 0;
        __syncthreads(); sh[t] += x; __syncthreads();
    }
    cur[b * 256 + t] = part[b] + sh[t] - v;
}
__global__ void sort_scatter(const int* __restrict__ key, const int* __restrict__ oth,
                             const int* __restrict__ at, int* __restrict__ cur,
                             int* __restrict__ oA, int* __restrict__ oB, int* __restrict__ oC)
{
    int e = blockIdx.x * 256 + threadIdx.x;
    if (e < NE) {
        int k = key[e];
        int p = atomicAdd(&cur[k], 1);
        oA[p] = k; oB[p] = oth[e]; oC[p] = at[e];
    }
}

// ---------------------------------------------------------------------------
// Weight packer: f32 row-major W (+rowoff/coloff) -> bf16 fragment file.
// ---------------------------------------------------------------------------
__global__ void pack_frag(const float* __restrict__ W, int ld, int rowoff, int coloff,
                          int nbs, int nbc, int KS, uint4* __restrict__ out)
{
    int tid = blockIdx.x * 256 + threadIdx.x;
    int total = nbc * KS * 512;
    if (tid >= total) return;
    int nbrel = tid / (KS * 512);
    int rem   = tid % (KS * 512);
    int ks = rem >> 9;
    int r2 = rem & 511;
    int nt = r2 >> 6, l = r2 & 63;
    int nb = nbs + nbrel;
    int k  = ks * 32 + (l >> 4) * 8;
    int col = nb * 128 + nt * 16 + (l & 15) + coloff;
    U16x8 u;
    #pragma unroll
    for (int j = 0; j < 8; ++j) u.s[j] = f2b(W[(size_t)(rowoff + k + j) * ld + col]);
    out[((size_t)(nb * KS + ks) * 8 + nt) * 64 + l] = u.u;
}

// ---------------------------------------------------------------------------
__global__ void ea_table_kernel(const float* __restrict__ emb_edge,
                                const float* __restrict__ We1, const float* __restrict__ be1,
                                const float* __restrict__ We2, const float* __restrict__ be2,
                                float* __restrict__ ea_tab)
{
    __shared__ float h1[3][128];
    const int j = threadIdx.x;
    for (int a = 0; a < 3; ++a) {
        float s = be1[j];
        for (int k = 0; k < 256; ++k) s = fmaf(emb_edge[a * 256 + k], We1[k * 128 + j], s);
        h1[a][j] = fmaxf(s, 0.f);
    }
    __syncthreads();
    for (int a = 0; a < 3; ++a) {
        float s = be2[j];
        for (int k = 0; k < 128; ++k) s = fmaf(h1[a][k], We2[k * 128 + j], s);
        ea_tab[a * 128 + j] = fmaxf(s, 0.f);
    }
}

__global__ void tpc_kernel(const float* __restrict__ ea_tab,
                           const float* __restrict__ Wp1, const float* __restrict__ bp1,
                           const float* __restrict__ Wc1, const float* __restrict__ bc1,
                           float* __restrict__ Tp, float* __restrict__ Tc)
{
    int j = threadIdx.x;
    for (int a = 0; a < 3; ++a) {
        float sp = bp1[j], sc = bc1[j];
        for (int k = 0; k < 128; ++k) {
            float e = ea_tab[a * 128 + k];
            sp = fmaf(e, Wp1[(size_t)(256 + k) * 256 + j], sp);
            sc = fmaf(e, Wc1[(size_t)(256 + k) * 256 + j], sc);
        }
        Tp[a * 256 + j] = sp;
        Tc[a * 256 + j] = sc;
    }
}

__global__ void deg_kernel(const int* __restrict__ src, float* __restrict__ deg)
{
    int i = blockIdx.x * 256 + threadIdx.x;
    if (i < NE) atomicAdd(deg + src[i], 1.0f);
}

// ---------------------------------------------------------------------------
extern "C" void kernel_launch(void* const* d_in, const int* in_sizes, int n_in,
                              void* d_out, int out_size, void* d_ws, size_t ws_size,
                              hipStream_t stream)
{
    const int*   x          = (const int*)d_in[0];
    const int*   edge_index = (const int*)d_in[1];
    const int*   edge_attr  = (const int*)d_in[2];
    const int*   batch_vec  = (const int*)d_in[3];
    const float* emb_node   = (const float*)d_in[4];
    const float* Wn1 = (const float*)d_in[5];  const float* bn1 = (const float*)d_in[6];
    const float* Wn2 = (const float*)d_in[7];  const float* bn2 = (const float*)d_in[8];
    const float* emb_edge = (const float*)d_in[9];
    const float* We1 = (const float*)d_in[10]; const float* be1 = (const float*)d_in[11];
    const float* We2 = (const float*)d_in[12]; const float* be2 = (const float*)d_in[13];
    const float* Wp1 = (const float*)d_in[14]; const float* bp1 = (const float*)d_in[15];
    const float* Wp2 = (const float*)d_in[16]; const float* bp2 = (const float*)d_in[17];
    const float* Wp3 = (const float*)d_in[18]; const float* bp3 = (const float*)d_in[19];
    const float* Wc1 = (const float*)d_in[20]; const float* bc1 = (const float*)d_in[21];
    const float* Wc2 = (const float*)d_in[22]; const float* bc2 = (const float*)d_in[23];
    const float* Wc3 = (const float*)d_in[24]; const float* bc3 = (const float*)d_in[25];
    const float* Wf1 = (const float*)d_in[26]; const float* bf1 = (const float*)d_in[27];
    const float* Wf2 = (const float*)d_in[28]; const float* bf2 = (const float*)d_in[29];
    const float* Wf3 = (const float*)d_in[30]; const float* bf3 = (const float*)d_in[31];
    const float* Wo1 = (const float*)d_in[32]; const float* bo1 = (const float*)d_in[33];
    const float* Wo2 = (const float*)d_in[34]; const float* bo2 = (const float*)d_in[35];

    float* out = (float*)d_out;

    char* w = (char*)d_ws;
    auto alloc = [&](size_t bytes) { char* p = w; w += (bytes + 255) & ~(size_t)255; return p; };
    float* nodes   = (float*)alloc((size_t)NN * DD * 4);
    u16*   nodesbf = (u16*)  alloc((size_t)NN * DD * 2);
    float* fi      = (float*)alloc((size_t)NN * DD * 4);
    float* fo      = (float*)alloc((size_t)NN * DD * 4);
    u16*   P       = (u16*)  alloc((size_t)NN * 512 * 2);
    u16*   h2      = (u16*)  alloc((size_t)NN * 384 * 2);
    float* deg     = (float*)alloc((size_t)NN * 4);
    float* ea_tab  = (float*)alloc(3 * 128 * 4);
    float* Tp      = (float*)alloc(3 * 256 * 4);
    float* Tc      = (float*)alloc(3 * 256 * 4);
    uint4* frag    = (uint4*)alloc((size_t)126976 * 16);
    int* histD = (int*)alloc(NBINS * 4);
    int* histS = (int*)alloc(NBINS * 4);
    int* partD = (int*)alloc(256 * 4);
    int* partS = (int*)alloc(256 * 4);
    int* curD  = (int*)alloc(NBINS * 4);
    int* curS  = (int*)alloc(NBINS * 4);
    int* sAp = (int*)alloc((size_t)NE * 4);
    int* sBp = (int*)alloc((size_t)NE * 4);
    int* sCp = (int*)alloc((size_t)NE * 4);
    int* sAc = (int*)alloc((size_t)NE * 4);
    int* sBc = (int*)alloc((size_t)NE * 4);
    int* sCc = (int*)alloc((size_t)NE * 4);

    u16* He = h2;                      // [50k][128]
    u16* U1 = h2;                      // [50k][256]
    u16* U2 = h2 + (size_t)NN * 256;   // [50k][128]
    u16* Hout1 = P;                    // [50k][512]

    uint4* Wn1f = frag;                // K256 N128
    uint4* Wn2f = Wn1f + 4096;         // K128 N128
    uint4* PWp  = Wn2f + 2048;         // K128 N512
    uint4* PWc  = PWp  + 8192;
    uint4* W2p  = PWc  + 8192;         // K256 N128
    uint4* W3p  = W2p  + 4096;         // K128 N128
    uint4* W2c  = W3p  + 2048;
    uint4* W3c  = W2c  + 4096;
    uint4* Wf1f = W3c  + 2048;         // K384 N256
    uint4* Wf2f = Wf1f + 12288;        // K256 N128
    uint4* Wf3f = Wf2f + 4096;         // K128 N128
    uint4* Wo1f = Wf3f + 2048;         // K128 N512
    uint4* Wo2f = Wo1f + 8192;         // K512 N1024

    const int* srcI = edge_index;
    const int* dstI = edge_index + NE;

    const int MB50 = (NN + 127) / 128;   // 391
    const int MBE  = (NE + 127) / 128;   // 1563
    const int MB64 = (NN + 63) / 64;     // 782

    auto pk = [&](const float* W, int ld, int rowoff, int coloff, int nbs, int nbc, int KS, uint4* o) {
        int total = nbc * KS * 512;
        pack_frag<<<(total + 255) / 256, 256, 0, stream>>>(W, ld, rowoff, coloff, nbs, nbc, KS, o);
    };

    (void)hipMemsetAsync(deg, 0, (size_t)NN * 4, stream);
    (void)hipMemsetAsync(d_out, 0, (size_t)out_size * 4, stream);
    (void)hipMemsetAsync(histD, 0, NBINS * 4, stream);
    (void)hipMemsetAsync(histS, 0, NBINS * 4, stream);

    pk(Wn1, 128, 0, 0, 0, 1, 8,  Wn1f);
    pk(Wn2, 128, 0, 0, 0, 1, 4,  Wn2f);
    pk(Wp1, 256, 0,    0, 0, 2, 4, PWp);
    pk(Wp1, 256, 128, -256, 2, 2, 4, PWp);
    pk(Wc1, 256, 0,    0, 0, 2, 4, PWc);
    pk(Wc1, 256, 128, -256, 2, 2, 4, PWc);
    pk(Wp2, 128, 0, 0, 0, 1, 8,  W2p);
    pk(Wp3, 128, 0, 0, 0, 1, 4,  W3p);
    pk(Wc2, 128, 0, 0, 0, 1, 8,  W2c);
    pk(Wc3, 128, 0, 0, 0, 1, 4,  W3c);
    pk(Wf1, 256, 0, 0, 0, 2, 12, Wf1f);
    pk(Wf2, 128, 0, 0, 0, 1, 8,  Wf2f);
    pk(Wf3, 128, 0, 0, 0, 1, 4,  Wf3f);
    pk(Wo1, 512, 0, 0, 0, 4, 4,  Wo1f);
    pk(Wo2, 1024, 0, 0, 0, 8, 16, Wo2f);

    ea_table_kernel<<<1, 128, 0, stream>>>(emb_edge, We1, be1, We2, be2, ea_tab);
    tpc_kernel<<<1, 256, 0, stream>>>(ea_tab, Wp1, bp1, Wc1, bc1, Tp, Tc);
    deg_kernel<<<(NE + 255) / 256, 256, 0, stream>>>(srcI, deg);

    hist_kernel<<<(NE + 255) / 256, 256, 0, stream>>>(dstI, histD);
    hist_kernel<<<(NE + 255) / 256, 256, 0, stream>>>(srcI, histS);
    chunk_sum<<<NPART, 256, 0, stream>>>(histD, partD);
    chunk_sum<<<NPART, 256, 0, stream>>>(histS, partS);
    scan_part<<<1, 256, 0, stream>>>(partD);
    scan_part<<<1, 256, 0, stream>>>(partS);
    mk_cursor<<<NPART, 256, 0, stream>>>(histD, partD, curD);
    mk_cursor<<<NPART, 256, 0, stream>>>(histS, partS, curS);
    sort_scatter<<<(NE + 255) / 256, 256, 0, stream>>>(dstI, srcI, edge_attr, curD, sAp, sBp, sCp);
    sort_scatter<<<(NE + 255) / 256, 256, 0, stream>>>(srcI, dstI, edge_attr, curS, sAc, sBc, sCc);

    // ---- node encoder ------------------------------------------------------
    gemm_k<256, 1, 0, true, SrcEnc><<<MB50, 256, 0, stream>>>(
        SrcEnc{emb_node, x}, Wn1f, bn1, EpiArgs{nullptr, He, nullptr, 128}, NN);
    expand_k<128, 1, 1, true, 128><<<MB50, 256, 0, stream>>>(
        He, Wn2f, bn2, nodes, nodesbf, NN);

    // ---- message-passing iterations ---------------------------------------
    for (int it = 0; it < NITERS; ++it) {
        (void)hipMemsetAsync(fi, 0, (size_t)2 * NN * DD * 4, stream);  // fi + fo

        expand_k<128, 4, 0, false, 512><<<MB50, 256, 0, stream>>>(
            nodesbf, PWp, nullptr, nullptr, P, NN);
        edge_fused<<<MBE, 256, 0, stream>>>(P, Tp, W2p, bp2, W3p, bp3,
                                            sAp, sBp, sCp, fi);

        expand_k<128, 4, 0, false, 512><<<MB50, 256, 0, stream>>>(
            nodesbf, PWc, nullptr, nullptr, P, NN);
        edge_fused<<<MBE, 256, 0, stream>>>(P, Tc, W2c, bc2, W3c, bc3,
                                            sAc, sBc, sCc, fo);

        gemm_k<384, 2, 0, true, SrcUpd><<<MB50 * 2, 256, 0, stream>>>(
            SrcUpd{nodes, fi, fo, deg}, Wf1f, bf1, EpiArgs{nullptr, U1, nullptr, 256}, NN);
        expand_k<256, 1, 0, true, 128><<<MB50, 256, 0, stream>>>(
            U1, Wf2f, bf2, nullptr, U2, NN);
        expand_k<128, 1, 2, true, 128><<<MB50, 256, 0, stream>>>(
            U2, Wf3f, bf3, nodes, nodesbf, NN);
    }

    // ---- output head + global max pool -------------------------------------
    expand_k<128, 4, 0, true, 512><<<MB50, 256, 0, stream>>>(
        nodesbf, Wo1f, bo1, nullptr, Hout1, NN);
    outhead_k<<<MB64, 256, 0, stream>>>(Hout1, Wo2f, bo2, batch_vec, out, NN);
}

// Round 8
// 971.310 us; speedup vs baseline: 2.9338x; 2.9338x over previous
//
#include <hip/hip_runtime.h>

#define NN 50000
#define NE 200000
#define DD 128
#define GG 256
#define NITERS 2
#define NBINS 50176          // 196 * 256, >= NN
#define NPART 196

typedef unsigned short u16;
typedef unsigned int u32;
typedef __bf16 bf16x8 __attribute__((ext_vector_type(8)));
typedef float f32x4 __attribute__((ext_vector_type(4)));

union U16x8 { uint4 u; bf16x8 v; u16 s[8]; };

__device__ __forceinline__ u16 f2b(float f) {             // f32 -> bf16 bits, RNE
    u32 u = __float_as_uint(f);
    return (u16)((u + 0x7FFFu + ((u >> 16) & 1u)) >> 16);
}
__device__ __forceinline__ float b2f(u16 s) { return __uint_as_float(((u32)s) << 16); }

__device__ __forceinline__ uint2 pack4(const float* v) {
    uint2 r;
    r.x = (u32)f2b(v[0]) | ((u32)f2b(v[1]) << 16);
    r.y = (u32)f2b(v[2]) | ((u32)f2b(v[3]) << 16);
    return r;
}

// async global -> LDS, 16B per lane; lds must be the wave-uniform base slot
__device__ __forceinline__ void gload_lds16(const void* g, void* lds) {
    __builtin_amdgcn_global_load_lds((const __attribute__((address_space(1))) void*)g,
                                     (__attribute__((address_space(3))) void*)lds, 16, 0, 0);
}

// XCD-chunked bijective block swizzle (m204 form)
__device__ __forceinline__ int xcd_swz(int orig, int nwg) {
    int q = nwg >> 3, r = nwg & 7;
    int x = orig & 7, loc = orig >> 3;
    return (x < r ? x * (q + 1) : r * (q + 1) + (x - r) * q) + loc;
}

// ---------------------------------------------------------------------------
// expand_k: OUT[128 rows][NL*128 cols] = epi(A[128][K] @ W + bias)
// A staged ONCE in LDS; W fragments per-lane direct global loads; swapped
// MFMA operands -> each thread owns 4 consecutive out-cols of one row.
// EPI: 0 = bf16 store (ob, ldN=LDN); 1 = f32 of + bf16 ob (LDN=128);
//      2 = residual: of += , ob mirror (LDN=128).
// ---------------------------------------------------------------------------
template<int K, int NL, int EPI, bool RELU, int LDN>
__global__ __launch_bounds__(256) void expand_k(
    const u16* __restrict__ A, const uint4* __restrict__ wfrag,
    const float* __restrict__ bias, float* __restrict__ of, u16* __restrict__ ob,
    int M)
{
    constexpr int KS = K / 32;
    __shared__ uint4 smem[K * 16];
    const int t = threadIdx.x, l = t & 63, wv = t >> 6;
    const int mh = wv >> 1, nh = wv & 1;
    const int mblk = blockIdx.x;

    #pragma unroll
    for (int i = 0; i < K / 16; ++i) {           // stage A once
        int s = t + 256 * i;
        int ln = s & 63, mt = (s >> 6) & 7, ksl = s >> 9;
        int row = mblk * 128 + mt * 16 + (ln & 15);
        if (row >= M) row = M - 1;
        int kk = ksl * 32 + (ln >> 4) * 8;
        gload_lds16(A + (size_t)row * K + kk, &smem[s - ln]);
    }
    __syncthreads();

    for (int c = 0; c < NL; ++c) {
        f32x4 acc[4][4] = {};
        #pragma unroll
        for (int ksl = 0; ksl < KS; ++ksl) {
            uint4 wa[4];
            #pragma unroll
            for (int mi = 0; mi < 4; ++mi)
                wa[mi] = wfrag[(size_t)((c * KS + ksl) * 8 + mh * 4 + mi) * 64 + l];
            bf16x8 bn[4];
            #pragma unroll
            for (int ni = 0; ni < 4; ++ni) { U16x8 u; u.u = smem[(ksl * 8 + nh * 4 + ni) * 64 + l]; bn[ni] = u.v; }
            #pragma unroll
            for (int mi = 0; mi < 4; ++mi) {
                U16x8 u; u.u = wa[mi];
                #pragma unroll
                for (int ni = 0; ni < 4; ++ni)
                    acc[mi][ni] = __builtin_amdgcn_mfma_f32_16x16x32_bf16(u.v, bn[ni], acc[mi][ni], 0, 0, 0);
            }
        }
        float4 bb[4];
        #pragma unroll
        for (int mi = 0; mi < 4; ++mi) {
            if (bias) bb[mi] = *(const float4*)(bias + c * 128 + mh * 64 + mi * 16 + 4 * (l >> 4));
            else { bb[mi].x = 0.f; bb[mi].y = 0.f; bb[mi].z = 0.f; bb[mi].w = 0.f; }
        }
        #pragma unroll
        for (int ni = 0; ni < 4; ++ni) {
            int node = mblk * 128 + nh * 64 + ni * 16 + (l & 15);
            if (node >= M) continue;
            #pragma unroll
            for (int mi = 0; mi < 4; ++mi) {
                int col = c * 128 + mh * 64 + mi * 16 + 4 * (l >> 4);
                float v[4];
                const float* bf = &bb[mi].x;
                #pragma unroll
                for (int r = 0; r < 4; ++r) {
                    v[r] = acc[mi][ni][r] + bf[r];
                    if (RELU) v[r] = fmaxf(v[r], 0.f);
                }
                if (EPI == 0) {
                    *(uint2*)(ob + (size_t)node * LDN + col) = pack4(v);
                } else {
                    size_t a = (size_t)node * 128 + col;
                    if (EPI == 2) {
                        float4 old = *(const float4*)(of + a);
                        v[0] += old.x; v[1] += old.y; v[2] += old.z; v[3] += old.w;
                    }
                    float4 s4; s4.x = v[0]; s4.y = v[1]; s4.z = v[2]; s4.w = v[3];
                    *(float4*)(of + a) = s4;
                    *(uint2*)(ob + a) = pack4(v);
                }
            }
        }
    }
}

// ---------------------------------------------------------------------------
// Source functors for A-operand staging (gemm_k).
// ---------------------------------------------------------------------------
struct SrcBf16 {            // plain bf16 row-major [M][K], async-staged
    static constexpr bool DIRECT = true;
    const u16* A; int K;
    __device__ const void* gaddr(int row, int kk) const { return A + (size_t)row * K + kk; }
    __device__ bf16x8 operator()(int row, int kk) const {
        U16x8 u; u.u = *(const uint4*)(A + (size_t)row * K + kk); return u.v;
    }
};
struct SrcEnc {             // node encoder input: emb_node[x[row]] (f32 -> bf16)
    static constexpr bool DIRECT = false;
    const float* emb; const int* xids;
    __device__ const void* gaddr(int, int) const { return nullptr; }
    __device__ bf16x8 operator()(int row, int kk) const {
        int n = xids[row];
        const float* p = emb + (size_t)n * 256 + kk;
        float4 f0 = *(const float4*)p, f1 = *(const float4*)(p + 4);
        U16x8 r;
        r.s[0]=f2b(f0.x); r.s[1]=f2b(f0.y); r.s[2]=f2b(f0.z); r.s[3]=f2b(f0.w);
        r.s[4]=f2b(f1.x); r.s[5]=f2b(f1.y); r.s[6]=f2b(f1.z); r.s[7]=f2b(f1.w);
        return r.v;
    }
};
struct SrcUpd {             // [nodes | deg_inv*fi | deg_inv*fo] (f32 -> bf16), K=384
    static constexpr bool DIRECT = false;
    const float* nodes; const float* fi; const float* fo; const float* deg;
    __device__ const void* gaddr(int, int) const { return nullptr; }
    __device__ bf16x8 operator()(int row, int kk) const {
        const float* s; float sc = 1.f;
        if (kk < 128) s = nodes + (size_t)row * 128 + kk;
        else {
            float d = deg[row];
            sc = d > 0.f ? 1.f / d : 0.f;
            s = (kk < 256) ? fi + (size_t)row * 128 + (kk - 128)
                           : fo + (size_t)row * 128 + (kk - 256);
        }
        float4 f0 = *(const float4*)s, f1 = *(const float4*)(s + 4);
        U16x8 r;
        r.s[0]=f2b(f0.x*sc); r.s[1]=f2b(f0.y*sc); r.s[2]=f2b(f0.z*sc); r.s[3]=f2b(f0.w*sc);
        r.s[4]=f2b(f1.x*sc); r.s[5]=f2b(f1.y*sc); r.s[6]=f2b(f1.z*sc); r.s[7]=f2b(f1.w*sc);
        return r.v;
    }
};

struct EpiArgs { float* of; u16* ob; const int* idx; int ldN; };

// ---------------------------------------------------------------------------
// gemm_k: non-swapped MFMA (C rows register-resident), used for computed
// staging layers (EPI0) and the output head segment-max (EPI3).
// EPI0: bf16 store via swizzled LDS bounce.
// EPI3: segment-max by sorted idx; ni-outer merge over 16 (mi,r) rows ->
//       ~1 atomic per lane per ni (16x merge).
// ---------------------------------------------------------------------------
template<int KDIM, int NBLK, int EPI, bool RELU, class SRC>
__global__ __launch_bounds__(256) void gemm_k(SRC src, const uint4* __restrict__ wfrag,
                                              const float* __restrict__ bias,
                                              EpiArgs ea, int M)
{
    constexpr int KS = KDIM / 32;
    constexpr int NPANEL = KDIM / 64;
    __shared__ uint4 smem[2048];
    const int t = threadIdx.x;
    const int l = t & 63;
    const int wv = t >> 6;
    const int mh = wv >> 1, nh = wv & 1;
    const int ell = xcd_swz(blockIdx.x, gridDim.x);
    const int mblk = ell / NBLK, nblk = ell % NBLK;

    f32x4 acc[4][4] = {};

    for (int p = 0; p < NPANEL; ++p) {
        __syncthreads();
        if constexpr (SRC::DIRECT) {
            #pragma unroll
            for (int i = 0; i < 4; ++i) {          // async A panel
                int s = t + 256 * i;
                int ln = s & 63, mt = (s >> 6) & 7, ksl = s >> 9;
                int row = mblk * 128 + mt * 16 + (ln & 15);
                if (row >= M) row = M - 1;
                int kk = p * 64 + ksl * 32 + (ln >> 4) * 8;
                gload_lds16(src.gaddr(row, kk), &smem[s - ln]);
            }
        } else {
            #pragma unroll
            for (int i = 0; i < 4; ++i) {          // computed A panel
                int s = t + 256 * i;
                int ln = s & 63, mt = (s >> 6) & 7, ksl = s >> 9;
                int row = mblk * 128 + mt * 16 + (ln & 15);
                if (row >= M) row = M - 1;
                int kk = p * 64 + ksl * 32 + (ln >> 4) * 8;
                U16x8 u; u.v = src(row, kk);
                smem[s] = u.u;
            }
        }
        {                                           // async W panel
            const uint4* wp = wfrag + (size_t)(nblk * KS + 2 * p) * 512;
            #pragma unroll
            for (int i = 0; i < 4; ++i) {
                int s = t + 256 * i;
                gload_lds16(wp + s, &smem[1024 + (s - (s & 63))]);
            }
        }
        __syncthreads();
        #pragma unroll
        for (int ksl = 0; ksl < 2; ++ksl) {
            bf16x8 a[4], b[4];
            #pragma unroll
            for (int mi = 0; mi < 4; ++mi) { U16x8 u; u.u = smem[(ksl*8 + mh*4 + mi)*64 + l]; a[mi] = u.v; }
            #pragma unroll
            for (int ni = 0; ni < 4; ++ni) { U16x8 u; u.u = smem[1024 + (ksl*8 + nh*4 + ni)*64 + l]; b[ni] = u.v; }
            #pragma unroll
            for (int mi = 0; mi < 4; ++mi)
                #pragma unroll
                for (int ni = 0; ni < 4; ++ni)
                    acc[mi][ni] = __builtin_amdgcn_mfma_f32_16x16x32_bf16(a[mi], b[ni], acc[mi][ni], 0, 0, 0);
        }
    }

    float bcol[4];
    #pragma unroll
    for (int ni = 0; ni < 4; ++ni)
        bcol[ni] = bias ? bias[nblk * 128 + nh * 64 + ni * 16 + (l & 15)] : 0.f;

    if (EPI == 0) {
        // bf16 store via XOR-swizzled LDS bounce
        __syncthreads();
        u16* bn = (u16*)smem;
        #pragma unroll
        for (int mi = 0; mi < 4; ++mi)
            #pragma unroll
            for (int ni = 0; ni < 4; ++ni)
                #pragma unroll
                for (int r = 0; r < 4; ++r) {
                    int rl = mh * 64 + mi * 16 + (l >> 4) * 4 + r;
                    int cl = nh * 64 + ni * 16 + (l & 15);
                    float v = acc[mi][ni][r] + bcol[ni];
                    if (RELU) v = fmaxf(v, 0.f);
                    int sx = (rl >> 2) & 7;
                    bn[rl * 128 + ((((cl >> 3) ^ sx)) << 3) + (cl & 7)] = f2b(v);
                }
        __syncthreads();
        int row = t >> 1, half = t & 1;
        int grow = mblk * 128 + row;
        if (grow < M) {
            int sx = (row >> 2) & 7;
            uint4* dst = (uint4*)(ea.ob + (size_t)grow * ea.ldN + nblk * 128 + half * 64);
            const uint4* sp = ((const uint4*)bn) + row * 16;
            #pragma unroll
            for (int i = 0; i < 8; ++i) dst[i] = sp[(half * 8 + i) ^ sx];
        }
    } else if (EPI == 3) {
        // segment-max: batch ids for this lane's 16 rows (within 64-row window)
        int g16[4][4];
        #pragma unroll
        for (int mi = 0; mi < 4; ++mi) {
            int rb = mblk * 128 + mh * 64 + mi * 16 + (l >> 4) * 4;
            #pragma unroll
            for (int r = 0; r < 4; ++r)
                g16[mi][r] = (rb + r < M) ? ea.idx[rb + r] : -1;
        }
        #pragma unroll
        for (int ni = 0; ni < 4; ++ni) {
            int colg = nblk * 128 + nh * 64 + ni * 16 + (l & 15);
            float mv = 0.f; int cg = -1;
            #pragma unroll
            for (int mi = 0; mi < 4; ++mi)
                #pragma unroll
                for (int r = 0; r < 4; ++r) {
                    float v = acc[mi][ni][r] + bcol[ni];
                    if (RELU) v = fmaxf(v, 0.f);
                    int g = g16[mi][r];
                    if (g != cg) {
                        if (cg >= 0) atomicMax((u32*)(ea.of + (size_t)cg * 1024 + colg), __float_as_uint(mv));
                        cg = g; mv = v;
                    } else mv = fmaxf(mv, v);
                }
            if (cg >= 0) atomicMax((u32*)(ea.of + (size_t)cg * 1024 + colg), __float_as_uint(mv));
        }
    }
}

// ---------------------------------------------------------------------------
// Fused per-edge pipeline (edges pre-sorted by idxA) — unchanged from R6.
// ---------------------------------------------------------------------------
__global__ __launch_bounds__(256) void edge_fused(
    const u16* __restrict__ P, const float* __restrict__ T,
    const uint4* __restrict__ W2f, const float* __restrict__ b2,
    const uint4* __restrict__ W3f, const float* __restrict__ b3,
    const int* __restrict__ idxA, const int* __restrict__ idxB,
    const int* __restrict__ eattr, float* __restrict__ agg)
{
    __shared__ uint4 smA[2048];
    __shared__ int   sidx[3][128];
    __shared__ float sT[768];
    const int t = threadIdx.x;
    const int l = t & 63;
    const int wv = t >> 6;
    const int mh = wv >> 1, nh = wv & 1;
    const int base = xcd_swz(blockIdx.x, gridDim.x) * 128;

    if (t < 128) {
        int e = (base + t < NE) ? base + t : NE - 1;
        sidx[0][t] = idxA[e];
        sidx[1][t] = idxB[e];
        sidx[2][t] = eattr[e];
    }
    for (int i = t; i < 768; i += 256) sT[i] = T[i];
    __syncthreads();

    const int rt0 = wv * 16 + (l & 15);
    const int rt1 = (wv + 4) * 16 + (l & 15);
    const int klo = (l >> 4) * 8;
    const u16* pA[2] = { P + (size_t)sidx[0][rt0] * 512, P + (size_t)sidx[0][rt1] * 512 };
    const u16* pB[2] = { P + (size_t)sidx[1][rt0] * 512 + 256, P + (size_t)sidx[1][rt1] * 512 + 256 };
    const float* pT[2] = { sT + sidx[2][rt0] * 256, sT + sidx[2][rt1] * 256 };

    uint4 ra[4], rb[4];
    #pragma unroll
    for (int i = 0; i < 4; ++i) {
        int kk = (i >> 1) * 32 + klo;
        ra[i] = *(const uint4*)(pA[i & 1] + kk);
        rb[i] = *(const uint4*)(pB[i & 1] + kk);
    }

    f32x4 acc[4][4] = {};
    #pragma unroll
    for (int p = 0; p < 4; ++p) {
        #pragma unroll
        for (int i = 0; i < 4; ++i) {
            int kk = (i >> 1) * 32 + klo;
            U16x8 ua, ub, r;
            ua.u = ra[i]; ub.u = rb[i];
            const float* tb = pT[i & 1] + p * 64 + kk;
            #pragma unroll
            for (int j = 0; j < 8; ++j) {
                float v = b2f(ua.s[j]) + b2f(ub.s[j]) + tb[j];
                r.s[j] = f2b(fmaxf(v, 0.f));
            }
            smA[(p & 1) * 1024 + t + 256 * i] = r.u;
            if (p < 3) {
                int kn = (p + 1) * 64 + kk;
                ra[i] = *(const uint4*)(pA[i & 1] + kn);
                rb[i] = *(const uint4*)(pB[i & 1] + kn);
            }
        }
        asm volatile("s_waitcnt lgkmcnt(0)" ::: "memory");
        __builtin_amdgcn_s_barrier();
        uint4 bw[2][4];
        #pragma unroll
        for (int ksl = 0; ksl < 2; ++ksl)
            #pragma unroll
            for (int ni = 0; ni < 4; ++ni)
                bw[ksl][ni] = W2f[(size_t)((p * 2 + ksl) * 8 + nh * 4 + ni) * 64 + l];
        #pragma unroll
        for (int ksl = 0; ksl < 2; ++ksl) {
            bf16x8 a[4];
            #pragma unroll
            for (int mi = 0; mi < 4; ++mi) { U16x8 u; u.u = smA[(p & 1) * 1024 + (ksl*8 + mh*4 + mi)*64 + l]; a[mi] = u.v; }
            #pragma unroll
            for (int mi = 0; mi < 4; ++mi)
                #pragma unroll
                for (int ni = 0; ni < 4; ++ni) {
                    U16x8 u; u.u = bw[ksl][ni];
                    acc[mi][ni] = __builtin_amdgcn_mfma_f32_16x16x32_bf16(a[mi], u.v, acc[mi][ni], 0, 0, 0);
                }
        }
    }

    float bc2[4];
    #pragma unroll
    for (int ni = 0; ni < 4; ++ni) bc2[ni] = b2[nh * 64 + ni * 16 + (l & 15)];
    __builtin_amdgcn_s_barrier();
    u16* bn = (u16*)smA;
    #pragma unroll
    for (int mi = 0; mi < 4; ++mi)
        #pragma unroll
        for (int ni = 0; ni < 4; ++ni)
            #pragma unroll
            for (int r = 0; r < 4; ++r) {
                int rl = mh * 64 + mi * 16 + (l >> 4) * 4 + r;
                int cl = nh * 64 + ni * 16 + (l & 15);
                float v = fmaxf(acc[mi][ni][r] + bc2[ni], 0.f);
                int sx = (rl >> 2) & 7;
                bn[rl * 128 + (((cl >> 3) ^ sx) << 3) + (cl & 7)] = f2b(v);
            }
    asm volatile("s_waitcnt lgkmcnt(0)" ::: "memory");
    __builtin_amdgcn_s_barrier();

    f32x4 acc2[4][4] = {};
    #pragma unroll
    for (int ks = 0; ks < 4; ++ks) {
        uint4 bw[4];
        #pragma unroll
        for (int ni = 0; ni < 4; ++ni)
            bw[ni] = W3f[(size_t)(ks * 8 + nh * 4 + ni) * 64 + l];
        bf16x8 a[4];
        #pragma unroll
        for (int mi = 0; mi < 4; ++mi) {
            int rl = (mh * 4 + mi) * 16 + (l & 15);
            int c0 = ks * 32 + (l >> 4) * 8;
            int sx = (rl >> 2) & 7;
            U16x8 u; u.u = *(const uint4*)&bn[rl * 128 + (((c0 >> 3) ^ sx) << 3)];
            a[mi] = u.v;
        }
        #pragma unroll
        for (int mi = 0; mi < 4; ++mi)
            #pragma unroll
            for (int ni = 0; ni < 4; ++ni) {
                U16x8 u; u.u = bw[ni];
                acc2[mi][ni] = __builtin_amdgcn_mfma_f32_16x16x32_bf16(a[mi], u.v, acc2[mi][ni], 0, 0, 0);
            }
    }

    float bc3[4];
    #pragma unroll
    for (int ni = 0; ni < 4; ++ni) bc3[ni] = b3[nh * 64 + ni * 16 + (l & 15)];
    #pragma unroll
    for (int mi = 0; mi < 4; ++mi) {
        int rt4 = mh * 64 + mi * 16 + (l >> 4) * 4;
        int nd[4];
        #pragma unroll
        for (int r = 0; r < 4; ++r)
            nd[r] = (base + rt4 + r < NE) ? sidx[0][rt4 + r] : -1;
        #pragma unroll
        for (int ni = 0; ni < 4; ++ni) {
            int col = nh * 64 + ni * 16 + (l & 15);
            float mv = 0.f; int cg = -1;
            #pragma unroll
            for (int r = 0; r < 4; ++r) {
                float v = fmaxf(acc2[mi][ni][r] + bc3[ni], 0.f);
                if (nd[r] != cg) {
                    if (cg >= 0) atomicAdd(agg + (size_t)cg * 128 + col, mv);
                    cg = nd[r]; mv = v;
                } else mv += v;
            }
            if (cg >= 0) atomicAdd(agg + (size_t)cg * 128 + col, mv);
        }
    }
}

// ---------------------------------------------------------------------------
// Counting sort of edges by key (dst or src), 50k bins.
// ---------------------------------------------------------------------------
__global__ void hist_kernel(const int* __restrict__ key, int* __restrict__ hist)
{
    int i = blockIdx.x * 256 + threadIdx.x;
    if (i < NE) atomicAdd(&hist[key[i]], 1);
}
__global__ void chunk_sum(const int* __restrict__ h, int* __restrict__ part)
{
    __shared__ int sh[256];
    int t = threadIdx.x, b = blockIdx.x;
    sh[t] = h[b * 256 + t];
    __syncthreads();
    for (int o = 128; o > 0; o >>= 1) { if (t < o) sh[t] += sh[t + o]; __syncthreads(); }
    if (t == 0) part[b] = sh[0];
}
__global__ void scan_part(int* part)
{
    __shared__ int sh[256];
    int t = threadIdx.x;
    sh[t] = (t < NPART) ? part[t] : 0;
    __syncthreads();
    for (int o = 1; o < 256; o <<= 1) {
        int x = (t >= o) ? sh[t - o] : 0;
        __syncthreads(); sh[t] += x; __syncthreads();
    }
    if (t < NPART) part[t] = t ? sh[t - 1] : 0;
}
__global__ void mk_cursor(const int* __restrict__ h, const int* __restrict__ part,
                          int* __restrict__ cur)
{
    __shared__ int sh[256];
    int t = threadIdx.x, b = blockIdx.x;
    int v = h[b * 256 + t];
    sh[t] = v;
    __syncthreads();
    for (int o = 1; o < 256; o <<= 1) {
        int x = (t >= o) ? sh[t - o] : 0;
        __syncthreads(); sh[t] += x; __syncthreads();
    }
    cur[b * 256 + t] = part[b] + sh[t] - v;
}
__global__ void sort_scatter(const int* __restrict__ key, const int* __restrict__ oth,
                             const int* __restrict__ at, int* __restrict__ cur,
                             int* __restrict__ oA, int* __restrict__ oB, int* __restrict__ oC)
{
    int e = blockIdx.x * 256 + threadIdx.x;
    if (e < NE) {
        int k = key[e];
        int p = atomicAdd(&cur[k], 1);
        oA[p] = k; oB[p] = oth[e]; oC[p] = at[e];
    }
}

// ---------------------------------------------------------------------------
// Weight packer: f32 row-major W (+rowoff/coloff) -> bf16 fragment file.
// ---------------------------------------------------------------------------
__global__ void pack_frag(const float* __restrict__ W, int ld, int rowoff, int coloff,
                          int nbs, int nbc, int KS, uint4* __restrict__ out)
{
    int tid = blockIdx.x * 256 + threadIdx.x;
    int total = nbc * KS * 512;
    if (tid >= total) return;
    int nbrel = tid / (KS * 512);
    int rem   = tid % (KS * 512);
    int ks = rem >> 9;
    int r2 = rem & 511;
    int nt = r2 >> 6, l = r2 & 63;
    int nb = nbs + nbrel;
    int k  = ks * 32 + (l >> 4) * 8;
    int col = nb * 128 + nt * 16 + (l & 15) + coloff;
    U16x8 u;
    #pragma unroll
    for (int j = 0; j < 8; ++j) u.s[j] = f2b(W[(size_t)(rowoff + k + j) * ld + col]);
    out[((size_t)(nb * KS + ks) * 8 + nt) * 64 + l] = u.u;
}

// ---------------------------------------------------------------------------
__global__ void ea_table_kernel(const float* __restrict__ emb_edge,
                                const float* __restrict__ We1, const float* __restrict__ be1,
                                const float* __restrict__ We2, const float* __restrict__ be2,
                                float* __restrict__ ea_tab)
{
    __shared__ float h1[3][128];
    const int j = threadIdx.x;
    for (int a = 0; a < 3; ++a) {
        float s = be1[j];
        for (int k = 0; k < 256; ++k) s = fmaf(emb_edge[a * 256 + k], We1[k * 128 + j], s);
        h1[a][j] = fmaxf(s, 0.f);
    }
    __syncthreads();
    for (int a = 0; a < 3; ++a) {
        float s = be2[j];
        for (int k = 0; k < 128; ++k) s = fmaf(h1[a][k], We2[k * 128 + j], s);
        ea_tab[a * 128 + j] = fmaxf(s, 0.f);
    }
}

__global__ void tpc_kernel(const float* __restrict__ ea_tab,
                           const float* __restrict__ Wp1, const float* __restrict__ bp1,
                           const float* __restrict__ Wc1, const float* __restrict__ bc1,
                           float* __restrict__ Tp, float* __restrict__ Tc)
{
    int j = threadIdx.x;
    for (int a = 0; a < 3; ++a) {
        float sp = bp1[j], sc = bc1[j];
        for (int k = 0; k < 128; ++k) {
            float e = ea_tab[a * 128 + k];
            sp = fmaf(e, Wp1[(size_t)(256 + k) * 256 + j], sp);
            sc = fmaf(e, Wc1[(size_t)(256 + k) * 256 + j], sc);
        }
        Tp[a * 256 + j] = sp;
        Tc[a * 256 + j] = sc;
    }
}

__global__ void deg_kernel(const int* __restrict__ src, float* __restrict__ deg)
{
    int i = blockIdx.x * 256 + threadIdx.x;
    if (i < NE) atomicAdd(deg + src[i], 1.0f);
}

// ---------------------------------------------------------------------------
extern "C" void kernel_launch(void* const* d_in, const int* in_sizes, int n_in,
                              void* d_out, int out_size, void* d_ws, size_t ws_size,
                              hipStream_t stream)
{
    const int*   x          = (const int*)d_in[0];
    const int*   edge_index = (const int*)d_in[1];
    const int*   edge_attr  = (const int*)d_in[2];
    const int*   batch_vec  = (const int*)d_in[3];
    const float* emb_node   = (const float*)d_in[4];
    const float* Wn1 = (const float*)d_in[5];  const float* bn1 = (const float*)d_in[6];
    const float* Wn2 = (const float*)d_in[7];  const float* bn2 = (const float*)d_in[8];
    const float* emb_edge = (const float*)d_in[9];
    const float* We1 = (const float*)d_in[10]; const float* be1 = (const float*)d_in[11];
    const float* We2 = (const float*)d_in[12]; const float* be2 = (const float*)d_in[13];
    const float* Wp1 = (const float*)d_in[14]; const float* bp1 = (const float*)d_in[15];
    const float* Wp2 = (const float*)d_in[16]; const float* bp2 = (const float*)d_in[17];
    const float* Wp3 = (const float*)d_in[18]; const float* bp3 = (const float*)d_in[19];
    const float* Wc1 = (const float*)d_in[20]; const float* bc1 = (const float*)d_in[21];
    const float* Wc2 = (const float*)d_in[22]; const float* bc2 = (const float*)d_in[23];
    const float* Wc3 = (const float*)d_in[24]; const float* bc3 = (const float*)d_in[25];
    const float* Wf1 = (const float*)d_in[26]; const float* bf1 = (const float*)d_in[27];
    const float* Wf2 = (const float*)d_in[28]; const float* bf2 = (const float*)d_in[29];
    const float* Wf3 = (const float*)d_in[30]; const float* bf3 = (const float*)d_in[31];
    const float* Wo1 = (const float*)d_in[32]; const float* bo1 = (const float*)d_in[33];
    const float* Wo2 = (const float*)d_in[34]; const float* bo2 = (const float*)d_in[35];

    float* out = (float*)d_out;

    char* w = (char*)d_ws;
    auto alloc = [&](size_t bytes) { char* p = w; w += (bytes + 255) & ~(size_t)255; return p; };
    float* nodes   = (float*)alloc((size_t)NN * DD * 4);
    u16*   nodesbf = (u16*)  alloc((size_t)NN * DD * 2);
    float* fi      = (float*)alloc((size_t)NN * DD * 4);
    float* fo      = (float*)alloc((size_t)NN * DD * 4);
    u16*   P       = (u16*)  alloc((size_t)NN * 512 * 2);
    u16*   h2      = (u16*)  alloc((size_t)NN * 384 * 2);
    float* deg     = (float*)alloc((size_t)NN * 4);
    float* ea_tab  = (float*)alloc(3 * 128 * 4);
    float* Tp      = (float*)alloc(3 * 256 * 4);
    float* Tc      = (float*)alloc(3 * 256 * 4);
    uint4* frag    = (uint4*)alloc((size_t)126976 * 16);
    int* histD = (int*)alloc(NBINS * 4);
    int* histS = (int*)alloc(NBINS * 4);
    int* partD = (int*)alloc(256 * 4);
    int* partS = (int*)alloc(256 * 4);
    int* curD  = (int*)alloc(NBINS * 4);
    int* curS  = (int*)alloc(NBINS * 4);
    int* sAp = (int*)alloc((size_t)NE * 4);
    int* sBp = (int*)alloc((size_t)NE * 4);
    int* sCp = (int*)alloc((size_t)NE * 4);
    int* sAc = (int*)alloc((size_t)NE * 4);
    int* sBc = (int*)alloc((size_t)NE * 4);
    int* sCc = (int*)alloc((size_t)NE * 4);

    u16* He = h2;                      // [50k][128]
    u16* U1 = h2;                      // [50k][256]
    u16* U2 = h2 + (size_t)NN * 256;   // [50k][128]
    u16* Hout1 = P;                    // [50k][512]

    uint4* Wn1f = frag;                // K256 N128
    uint4* Wn2f = Wn1f + 4096;         // K128 N128
    uint4* PWp  = Wn2f + 2048;         // K128 N512
    uint4* PWc  = PWp  + 8192;
    uint4* W2p  = PWc  + 8192;         // K256 N128
    uint4* W3p  = W2p  + 4096;         // K128 N128
    uint4* W2c  = W3p  + 2048;
    uint4* W3c  = W2c  + 4096;
    uint4* Wf1f = W3c  + 2048;         // K384 N256
    uint4* Wf2f = Wf1f + 12288;        // K256 N128
    uint4* Wf3f = Wf2f + 4096;         // K128 N128
    uint4* Wo1f = Wf3f + 2048;         // K128 N512
    uint4* Wo2f = Wo1f + 8192;         // K512 N1024

    const int* srcI = edge_index;
    const int* dstI = edge_index + NE;

    const int MB50 = (NN + 127) / 128;   // 391
    const int MBE  = (NE + 127) / 128;   // 1563

    auto pk = [&](const float* W, int ld, int rowoff, int coloff, int nbs, int nbc, int KS, uint4* o) {
        int total = nbc * KS * 512;
        pack_frag<<<(total + 255) / 256, 256, 0, stream>>>(W, ld, rowoff, coloff, nbs, nbc, KS, o);
    };

    (void)hipMemsetAsync(deg, 0, (size_t)NN * 4, stream);
    (void)hipMemsetAsync(d_out, 0, (size_t)out_size * 4, stream);
    (void)hipMemsetAsync(histD, 0, NBINS * 4, stream);
    (void)hipMemsetAsync(histS, 0, NBINS * 4, stream);

    pk(Wn1, 128, 0, 0, 0, 1, 8,  Wn1f);
    pk(Wn2, 128, 0, 0, 0, 1, 4,  Wn2f);
    pk(Wp1, 256, 0,    0, 0, 2, 4, PWp);
    pk(Wp1, 256, 128, -256, 2, 2, 4, PWp);
    pk(Wc1, 256, 0,    0, 0, 2, 4, PWc);
    pk(Wc1, 256, 128, -256, 2, 2, 4, PWc);
    pk(Wp2, 128, 0, 0, 0, 1, 8,  W2p);
    pk(Wp3, 128, 0, 0, 0, 1, 4,  W3p);
    pk(Wc2, 128, 0, 0, 0, 1, 8,  W2c);
    pk(Wc3, 128, 0, 0, 0, 1, 4,  W3c);
    pk(Wf1, 256, 0, 0, 0, 2, 12, Wf1f);
    pk(Wf2, 128, 0, 0, 0, 1, 8,  Wf2f);
    pk(Wf3, 128, 0, 0, 0, 1, 4,  Wf3f);
    pk(Wo1, 512, 0, 0, 0, 4, 4,  Wo1f);
    pk(Wo2, 1024, 0, 0, 0, 8, 16, Wo2f);

    ea_table_kernel<<<1, 128, 0, stream>>>(emb_edge, We1, be1, We2, be2, ea_tab);
    tpc_kernel<<<1, 256, 0, stream>>>(ea_tab, Wp1, bp1, Wc1, bc1, Tp, Tc);
    deg_kernel<<<(NE + 255) / 256, 256, 0, stream>>>(srcI, deg);

    hist_kernel<<<(NE + 255) / 256, 256, 0, stream>>>(dstI, histD);
    hist_kernel<<<(NE + 255) / 256, 256, 0, stream>>>(srcI, histS);
    chunk_sum<<<NPART, 256, 0, stream>>>(histD, partD);
    chunk_sum<<<NPART, 256, 0, stream>>>(histS, partS);
    scan_part<<<1, 256, 0, stream>>>(partD);
    scan_part<<<1, 256, 0, stream>>>(partS);
    mk_cursor<<<NPART, 256, 0, stream>>>(histD, partD, curD);
    mk_cursor<<<NPART, 256, 0, stream>>>(histS, partS, curS);
    sort_scatter<<<(NE + 255) / 256, 256, 0, stream>>>(dstI, srcI, edge_attr, curD, sAp, sBp, sCp);
    sort_scatter<<<(NE + 255) / 256, 256, 0, stream>>>(srcI, dstI, edge_attr, curS, sAc, sBc, sCc);

    // ---- node encoder ------------------------------------------------------
    gemm_k<256, 1, 0, true, SrcEnc><<<MB50, 256, 0, stream>>>(
        SrcEnc{emb_node, x}, Wn1f, bn1, EpiArgs{nullptr, He, nullptr, 128}, NN);
    expand_k<128, 1, 1, true, 128><<<MB50, 256, 0, stream>>>(
        He, Wn2f, bn2, nodes, nodesbf, NN);

    // ---- message-passing iterations ---------------------------------------
    for (int it = 0; it < NITERS; ++it) {
        (void)hipMemsetAsync(fi, 0, (size_t)2 * NN * DD * 4, stream);  // fi + fo

        expand_k<128, 4, 0, false, 512><<<MB50, 256, 0, stream>>>(
            nodesbf, PWp, nullptr, nullptr, P, NN);
        edge_fused<<<MBE, 256, 0, stream>>>(P, Tp, W2p, bp2, W3p, bp3,
                                            sAp, sBp, sCp, fi);

        expand_k<128, 4, 0, false, 512><<<MB50, 256, 0, stream>>>(
            nodesbf, PWc, nullptr, nullptr, P, NN);
        edge_fused<<<MBE, 256, 0, stream>>>(P, Tc, W2c, bc2, W3c, bc3,
                                            sAc, sBc, sCc, fo);

        gemm_k<384, 2, 0, true, SrcUpd><<<MB50 * 2, 256, 0, stream>>>(
            SrcUpd{nodes, fi, fo, deg}, Wf1f, bf1, EpiArgs{nullptr, U1, nullptr, 256}, NN);
        expand_k<256, 1, 0, true, 128><<<MB50, 256, 0, stream>>>(
            U1, Wf2f, bf2, nullptr, U2, NN);
        expand_k<128, 1, 2, true, 128><<<MB50, 256, 0, stream>>>(
            U2, Wf3f, bf3, nodes, nodesbf, NN);
    }

    // ---- output head + global max pool -------------------------------------
    expand_k<128, 4, 0, true, 512><<<MB50, 256, 0, stream>>>(
        nodesbf, Wo1f, bo1, nullptr, Hout1, NN);
    gemm_k<512, 8, 3, true, SrcBf16><<<MB50 * 8, 256, 0, stream>>>(
        SrcBf16{Hout1, 512}, Wo2f, bo2, EpiArgs{out, nullptr, batch_vec, 1024}, NN);
}

// Round 9
// 917.044 us; speedup vs baseline: 3.1074x; 1.0592x over previous
//
#include <hip/hip_runtime.h>

#define NN 50000
#define NE 200000
#define DD 128
#define GG 256
#define NITERS 2
#define NBINS 50176          // 196 * 256, >= NN
#define NPART 196

typedef unsigned short u16;
typedef unsigned int u32;
typedef __bf16 bf16x8 __attribute__((ext_vector_type(8)));
typedef float f32x4 __attribute__((ext_vector_type(4)));

union U16x8 { uint4 u; bf16x8 v; u16 s[8]; };

__device__ __forceinline__ u16 f2b(float f) {             // f32 -> bf16 bits, RNE
    u32 u = __float_as_uint(f);
    return (u16)((u + 0x7FFFu + ((u >> 16) & 1u)) >> 16);
}
__device__ __forceinline__ float b2f(u16 s) { return __uint_as_float(((u32)s) << 16); }

__device__ __forceinline__ uint2 pack4(const float* v) {
    uint2 r;
    r.x = (u32)f2b(v[0]) | ((u32)f2b(v[1]) << 16);
    r.y = (u32)f2b(v[2]) | ((u32)f2b(v[3]) << 16);
    return r;
}

// async global -> LDS, 16B per lane; lds must be the wave-uniform base slot
__device__ __forceinline__ void gload_lds16(const void* g, void* lds) {
    __builtin_amdgcn_global_load_lds((const __attribute__((address_space(1))) void*)g,
                                     (__attribute__((address_space(3))) void*)lds, 16, 0, 0);
}

// XCD-chunked bijective block swizzle (m204 form)
__device__ __forceinline__ int xcd_swz(int orig, int nwg) {
    int q = nwg >> 3, r = nwg & 7;
    int x = orig & 7, loc = orig >> 3;
    return (x < r ? x * (q + 1) : r * (q + 1) + (x - r) * q) + loc;
}

// ---------------------------------------------------------------------------
// expand_k: OUT[128 rows][cols c*128..] = epi(A[128][K] @ W + bias), c = blockIdx.y
// A staged ONCE in LDS; W fragments per-lane direct global loads; swapped
// MFMA operands -> each thread owns 4 consecutive out-cols of one row.
// EPI: 0 = bf16 store (ob, ldN=LDN); 1 = f32 of + bf16 ob (LDN=128);
//      2 = residual: of += , ob mirror (LDN=128).
// ---------------------------------------------------------------------------
template<int K, int NL, int EPI, bool RELU, int LDN>
__global__ __launch_bounds__(256) void expand_k(
    const u16* __restrict__ A, const uint4* __restrict__ wfrag,
    const float* __restrict__ bias, float* __restrict__ of, u16* __restrict__ ob,
    int M)
{
    constexpr int KS = K / 32;
    __shared__ uint4 smem[K * 16];
    const int t = threadIdx.x, l = t & 63, wv = t >> 6;
    const int mh = wv >> 1, nh = wv & 1;
    const int mblk = blockIdx.x;
    const int c = blockIdx.y;

    #pragma unroll
    for (int i = 0; i < K / 16; ++i) {           // stage A once
        int s = t + 256 * i;
        int ln = s & 63, mt = (s >> 6) & 7, ksl = s >> 9;
        int row = mblk * 128 + mt * 16 + (ln & 15);
        if (row >= M) row = M - 1;
        int kk = ksl * 32 + (ln >> 4) * 8;
        gload_lds16(A + (size_t)row * K + kk, &smem[s - ln]);
    }
    __syncthreads();

    f32x4 acc[4][4] = {};
    #pragma unroll
    for (int ksl = 0; ksl < KS; ++ksl) {
        uint4 wa[4];
        #pragma unroll
        for (int mi = 0; mi < 4; ++mi)
            wa[mi] = wfrag[(size_t)((c * KS + ksl) * 8 + mh * 4 + mi) * 64 + l];
        bf16x8 bn[4];
        #pragma unroll
        for (int ni = 0; ni < 4; ++ni) { U16x8 u; u.u = smem[(ksl * 8 + nh * 4 + ni) * 64 + l]; bn[ni] = u.v; }
        #pragma unroll
        for (int mi = 0; mi < 4; ++mi) {
            U16x8 u; u.u = wa[mi];
            #pragma unroll
            for (int ni = 0; ni < 4; ++ni)
                acc[mi][ni] = __builtin_amdgcn_mfma_f32_16x16x32_bf16(u.v, bn[ni], acc[mi][ni], 0, 0, 0);
        }
    }
    float4 bb[4];
    #pragma unroll
    for (int mi = 0; mi < 4; ++mi) {
        if (bias) bb[mi] = *(const float4*)(bias + c * 128 + mh * 64 + mi * 16 + 4 * (l >> 4));
        else { bb[mi].x = 0.f; bb[mi].y = 0.f; bb[mi].z = 0.f; bb[mi].w = 0.f; }
    }
    #pragma unroll
    for (int ni = 0; ni < 4; ++ni) {
        int node = mblk * 128 + nh * 64 + ni * 16 + (l & 15);
        if (node >= M) continue;
        #pragma unroll
        for (int mi = 0; mi < 4; ++mi) {
            int col = c * 128 + mh * 64 + mi * 16 + 4 * (l >> 4);
            float v[4];
            const float* bf = &bb[mi].x;
            #pragma unroll
            for (int r = 0; r < 4; ++r) {
                v[r] = acc[mi][ni][r] + bf[r];
                if (RELU) v[r] = fmaxf(v[r], 0.f);
            }
            if (EPI == 0) {
                *(uint2*)(ob + (size_t)node * LDN + col) = pack4(v);
            } else {
                size_t a = (size_t)node * 128 + col;
                if (EPI == 2) {
                    float4 old = *(const float4*)(of + a);
                    v[0] += old.x; v[1] += old.y; v[2] += old.z; v[3] += old.w;
                }
                float4 s4; s4.x = v[0]; s4.y = v[1]; s4.z = v[2]; s4.w = v[3];
                *(float4*)(of + a) = s4;
                *(uint2*)(ob + a) = pack4(v);
            }
        }
    }
}

// ---------------------------------------------------------------------------
// Source functors for A-operand staging (gemm_k).
// ---------------------------------------------------------------------------
struct SrcBf16 {            // plain bf16 row-major [M][K], async-staged
    static constexpr bool DIRECT = true;
    const u16* A; int K;
    __device__ const void* gaddr(int row, int kk) const { return A + (size_t)row * K + kk; }
    __device__ bf16x8 operator()(int row, int kk) const {
        U16x8 u; u.u = *(const uint4*)(A + (size_t)row * K + kk); return u.v;
    }
};
struct SrcEnc {             // node encoder input: emb_node[x[row]] (f32 -> bf16)
    static constexpr bool DIRECT = false;
    const float* emb; const int* xids;
    __device__ const void* gaddr(int, int) const { return nullptr; }
    __device__ bf16x8 operator()(int row, int kk) const {
        int n = xids[row];
        const float* p = emb + (size_t)n * 256 + kk;
        float4 f0 = *(const float4*)p, f1 = *(const float4*)(p + 4);
        U16x8 r;
        r.s[0]=f2b(f0.x); r.s[1]=f2b(f0.y); r.s[2]=f2b(f0.z); r.s[3]=f2b(f0.w);
        r.s[4]=f2b(f1.x); r.s[5]=f2b(f1.y); r.s[6]=f2b(f1.z); r.s[7]=f2b(f1.w);
        return r.v;
    }
};
struct SrcUpd {             // [nodes | fi/deg | fo/deg] (f32 -> bf16), K=384
    static constexpr bool DIRECT = false;
    const float* nodes; const float* fi; const float* fo; const int* deg;
    __device__ const void* gaddr(int, int) const { return nullptr; }
    __device__ bf16x8 operator()(int row, int kk) const {
        const float* s; float sc = 1.f;
        if (kk < 128) s = nodes + (size_t)row * 128 + kk;
        else {
            int d = deg[row];
            sc = d > 0 ? 1.f / (float)d : 0.f;
            s = (kk < 256) ? fi + (size_t)row * 128 + (kk - 128)
                           : fo + (size_t)row * 128 + (kk - 256);
        }
        float4 f0 = *(const float4*)s, f1 = *(const float4*)(s + 4);
        U16x8 r;
        r.s[0]=f2b(f0.x*sc); r.s[1]=f2b(f0.y*sc); r.s[2]=f2b(f0.z*sc); r.s[3]=f2b(f0.w*sc);
        r.s[4]=f2b(f1.x*sc); r.s[5]=f2b(f1.y*sc); r.s[6]=f2b(f1.z*sc); r.s[7]=f2b(f1.w*sc);
        return r.v;
    }
};

struct EpiArgs { float* of; u16* ob; const int* idx; int ldN; };

// ---------------------------------------------------------------------------
// gemm_k: non-swapped MFMA (C rows register-resident).
// EPI0: bf16 store via swizzled LDS bounce.
// EPI3: segment-max by sorted idx; ni-outer merge over 16 (mi,r) rows.
// ---------------------------------------------------------------------------
template<int KDIM, int NBLK, int EPI, bool RELU, class SRC>
__global__ __launch_bounds__(256) void gemm_k(SRC src, const uint4* __restrict__ wfrag,
                                              const float* __restrict__ bias,
                                              EpiArgs ea, int M)
{
    constexpr int KS = KDIM / 32;
    constexpr int NPANEL = KDIM / 64;
    __shared__ uint4 smem[2048];
    const int t = threadIdx.x;
    const int l = t & 63;
    const int wv = t >> 6;
    const int mh = wv >> 1, nh = wv & 1;
    const int ell = xcd_swz(blockIdx.x, gridDim.x);
    const int mblk = ell / NBLK, nblk = ell % NBLK;

    f32x4 acc[4][4] = {};

    for (int p = 0; p < NPANEL; ++p) {
        __syncthreads();
        if constexpr (SRC::DIRECT) {
            #pragma unroll
            for (int i = 0; i < 4; ++i) {          // async A panel
                int s = t + 256 * i;
                int ln = s & 63, mt = (s >> 6) & 7, ksl = s >> 9;
                int row = mblk * 128 + mt * 16 + (ln & 15);
                if (row >= M) row = M - 1;
                int kk = p * 64 + ksl * 32 + (ln >> 4) * 8;
                gload_lds16(src.gaddr(row, kk), &smem[s - ln]);
            }
        } else {
            #pragma unroll
            for (int i = 0; i < 4; ++i) {          // computed A panel
                int s = t + 256 * i;
                int ln = s & 63, mt = (s >> 6) & 7, ksl = s >> 9;
                int row = mblk * 128 + mt * 16 + (ln & 15);
                if (row >= M) row = M - 1;
                int kk = p * 64 + ksl * 32 + (ln >> 4) * 8;
                U16x8 u; u.v = src(row, kk);
                smem[s] = u.u;
            }
        }
        {                                           // async W panel
            const uint4* wp = wfrag + (size_t)(nblk * KS + 2 * p) * 512;
            #pragma unroll
            for (int i = 0; i < 4; ++i) {
                int s = t + 256 * i;
                gload_lds16(wp + s, &smem[1024 + (s - (s & 63))]);
            }
        }
        __syncthreads();
        #pragma unroll
        for (int ksl = 0; ksl < 2; ++ksl) {
            bf16x8 a[4], b[4];
            #pragma unroll
            for (int mi = 0; mi < 4; ++mi) { U16x8 u; u.u = smem[(ksl*8 + mh*4 + mi)*64 + l]; a[mi] = u.v; }
            #pragma unroll
            for (int ni = 0; ni < 4; ++ni) { U16x8 u; u.u = smem[1024 + (ksl*8 + nh*4 + ni)*64 + l]; b[ni] = u.v; }
            #pragma unroll
            for (int mi = 0; mi < 4; ++mi)
                #pragma unroll
                for (int ni = 0; ni < 4; ++ni)
                    acc[mi][ni] = __builtin_amdgcn_mfma_f32_16x16x32_bf16(a[mi], b[ni], acc[mi][ni], 0, 0, 0);
        }
    }

    float bcol[4];
    #pragma unroll
    for (int ni = 0; ni < 4; ++ni)
        bcol[ni] = bias ? bias[nblk * 128 + nh * 64 + ni * 16 + (l & 15)] : 0.f;

    if (EPI == 0) {
        __syncthreads();
        u16* bn = (u16*)smem;
        #pragma unroll
        for (int mi = 0; mi < 4; ++mi)
            #pragma unroll
            for (int ni = 0; ni < 4; ++ni)
                #pragma unroll
                for (int r = 0; r < 4; ++r) {
                    int rl = mh * 64 + mi * 16 + (l >> 4) * 4 + r;
                    int cl = nh * 64 + ni * 16 + (l & 15);
                    float v = acc[mi][ni][r] + bcol[ni];
                    if (RELU) v = fmaxf(v, 0.f);
                    int sx = (rl >> 2) & 7;
                    bn[rl * 128 + ((((cl >> 3) ^ sx)) << 3) + (cl & 7)] = f2b(v);
                }
        __syncthreads();
        int row = t >> 1, half = t & 1;
        int grow = mblk * 128 + row;
        if (grow < M) {
            int sx = (row >> 2) & 7;
            uint4* dst = (uint4*)(ea.ob + (size_t)grow * ea.ldN + nblk * 128 + half * 64);
            const uint4* sp = ((const uint4*)bn) + row * 16;
            #pragma unroll
            for (int i = 0; i < 8; ++i) dst[i] = sp[(half * 8 + i) ^ sx];
        }
    } else if (EPI == 3) {
        int g16[4][4];
        #pragma unroll
        for (int mi = 0; mi < 4; ++mi) {
            int rb = mblk * 128 + mh * 64 + mi * 16 + (l >> 4) * 4;
            #pragma unroll
            for (int r = 0; r < 4; ++r)
                g16[mi][r] = (rb + r < M) ? ea.idx[rb + r] : -1;
        }
        #pragma unroll
        for (int ni = 0; ni < 4; ++ni) {
            int colg = nblk * 128 + nh * 64 + ni * 16 + (l & 15);
            float mv = 0.f; int cg = -1;
            #pragma unroll
            for (int mi = 0; mi < 4; ++mi)
                #pragma unroll
                for (int r = 0; r < 4; ++r) {
                    float v = acc[mi][ni][r] + bcol[ni];
                    if (RELU) v = fmaxf(v, 0.f);
                    int g = g16[mi][r];
                    if (g != cg) {
                        if (cg >= 0) atomicMax((u32*)(ea.of + (size_t)cg * 1024 + colg), __float_as_uint(mv));
                        cg = g; mv = v;
                    } else mv = fmaxf(mv, v);
                }
            if (cg >= 0) atomicMax((u32*)(ea.of + (size_t)cg * 1024 + colg), __float_as_uint(mv));
        }
    }
}

// ---------------------------------------------------------------------------
// Fused per-edge pipeline (edges pre-sorted by idxA) — unchanged from R6.
// ---------------------------------------------------------------------------
__global__ __launch_bounds__(256) void edge_fused(
    const u16* __restrict__ P, const float* __restrict__ T,
    const uint4* __restrict__ W2f, const float* __restrict__ b2,
    const uint4* __restrict__ W3f, const float* __restrict__ b3,
    const int* __restrict__ idxA, const int* __restrict__ idxB,
    const int* __restrict__ eattr, float* __restrict__ agg)
{
    __shared__ uint4 smA[2048];
    __shared__ int   sidx[3][128];
    __shared__ float sT[768];
    const int t = threadIdx.x;
    const int l = t & 63;
    const int wv = t >> 6;
    const int mh = wv >> 1, nh = wv & 1;
    const int base = xcd_swz(blockIdx.x, gridDim.x) * 128;

    if (t < 128) {
        int e = (base + t < NE) ? base + t : NE - 1;
        sidx[0][t] = idxA[e];
        sidx[1][t] = idxB[e];
        sidx[2][t] = eattr[e];
    }
    for (int i = t; i < 768; i += 256) sT[i] = T[i];
    __syncthreads();

    const int rt0 = wv * 16 + (l & 15);
    const int rt1 = (wv + 4) * 16 + (l & 15);
    const int klo = (l >> 4) * 8;
    const u16* pA[2] = { P + (size_t)sidx[0][rt0] * 512, P + (size_t)sidx[0][rt1] * 512 };
    const u16* pB[2] = { P + (size_t)sidx[1][rt0] * 512 + 256, P + (size_t)sidx[1][rt1] * 512 + 256 };
    const float* pT[2] = { sT + sidx[2][rt0] * 256, sT + sidx[2][rt1] * 256 };

    uint4 ra[4], rb[4];
    #pragma unroll
    for (int i = 0; i < 4; ++i) {
        int kk = (i >> 1) * 32 + klo;
        ra[i] = *(const uint4*)(pA[i & 1] + kk);
        rb[i] = *(const uint4*)(pB[i & 1] + kk);
    }

    f32x4 acc[4][4] = {};
    #pragma unroll
    for (int p = 0; p < 4; ++p) {
        #pragma unroll
        for (int i = 0; i < 4; ++i) {
            int kk = (i >> 1) * 32 + klo;
            U16x8 ua, ub, r;
            ua.u = ra[i]; ub.u = rb[i];
            const float* tb = pT[i & 1] + p * 64 + kk;
            #pragma unroll
            for (int j = 0; j < 8; ++j) {
                float v = b2f(ua.s[j]) + b2f(ub.s[j]) + tb[j];
                r.s[j] = f2b(fmaxf(v, 0.f));
            }
            smA[(p & 1) * 1024 + t + 256 * i] = r.u;
            if (p < 3) {
                int kn = (p + 1) * 64 + kk;
                ra[i] = *(const uint4*)(pA[i & 1] + kn);
                rb[i] = *(const uint4*)(pB[i & 1] + kn);
            }
        }
        asm volatile("s_waitcnt lgkmcnt(0)" ::: "memory");
        __builtin_amdgcn_s_barrier();
        uint4 bw[2][4];
        #pragma unroll
        for (int ksl = 0; ksl < 2; ++ksl)
            #pragma unroll
            for (int ni = 0; ni < 4; ++ni)
                bw[ksl][ni] = W2f[(size_t)((p * 2 + ksl) * 8 + nh * 4 + ni) * 64 + l];
        #pragma unroll
        for (int ksl = 0; ksl < 2; ++ksl) {
            bf16x8 a[4];
            #pragma unroll
            for (int mi = 0; mi < 4; ++mi) { U16x8 u; u.u = smA[(p & 1) * 1024 + (ksl*8 + mh*4 + mi)*64 + l]; a[mi] = u.v; }
            #pragma unroll
            for (int mi = 0; mi < 4; ++mi)
                #pragma unroll
                for (int ni = 0; ni < 4; ++ni) {
                    U16x8 u; u.u = bw[ksl][ni];
                    acc[mi][ni] = __builtin_amdgcn_mfma_f32_16x16x32_bf16(a[mi], u.v, acc[mi][ni], 0, 0, 0);
                }
        }
    }

    float bc2[4];
    #pragma unroll
    for (int ni = 0; ni < 4; ++ni) bc2[ni] = b2[nh * 64 + ni * 16 + (l & 15)];
    __builtin_amdgcn_s_barrier();
    u16* bn = (u16*)smA;
    #pragma unroll
    for (int mi = 0; mi < 4; ++mi)
        #pragma unroll
        for (int ni = 0; ni < 4; ++ni)
            #pragma unroll
            for (int r = 0; r < 4; ++r) {
                int rl = mh * 64 + mi * 16 + (l >> 4) * 4 + r;
                int cl = nh * 64 + ni * 16 + (l & 15);
                float v = fmaxf(acc[mi][ni][r] + bc2[ni], 0.f);
                int sx = (rl >> 2) & 7;
                bn[rl * 128 + (((cl >> 3) ^ sx) << 3) + (cl & 7)] = f2b(v);
            }
    asm volatile("s_waitcnt lgkmcnt(0)" ::: "memory");
    __builtin_amdgcn_s_barrier();

    f32x4 acc2[4][4] = {};
    #pragma unroll
    for (int ks = 0; ks < 4; ++ks) {
        uint4 bw[4];
        #pragma unroll
        for (int ni = 0; ni < 4; ++ni)
            bw[ni] = W3f[(size_t)(ks * 8 + nh * 4 + ni) * 64 + l];
        bf16x8 a[4];
        #pragma unroll
        for (int mi = 0; mi < 4; ++mi) {
            int rl = (mh * 4 + mi) * 16 + (l & 15);
            int c0 = ks * 32 + (l >> 4) * 8;
            int sx = (rl >> 2) & 7;
            U16x8 u; u.u = *(const uint4*)&bn[rl * 128 + (((c0 >> 3) ^ sx) << 3)];
            a[mi] = u.v;
        }
        #pragma unroll
        for (int mi = 0; mi < 4; ++mi)
            #pragma unroll
            for (int ni = 0; ni < 4; ++ni) {
                U16x8 u; u.u = bw[ni];
                acc2[mi][ni] = __builtin_amdgcn_mfma_f32_16x16x32_bf16(a[mi], u.v, acc2[mi][ni], 0, 0, 0);
            }
    }

    float bc3[4];
    #pragma unroll
    for (int ni = 0; ni < 4; ++ni) bc3[ni] = b3[nh * 64 + ni * 16 + (l & 15)];
    #pragma unroll
    for (int mi = 0; mi < 4; ++mi) {
        int rt4 = mh * 64 + mi * 16 + (l >> 4) * 4;
        int nd[4];
        #pragma unroll
        for (int r = 0; r < 4; ++r)
            nd[r] = (base + rt4 + r < NE) ? sidx[0][rt4 + r] : -1;
        #pragma unroll
        for (int ni = 0; ni < 4; ++ni) {
            int col = nh * 64 + ni * 16 + (l & 15);
            float mv = 0.f; int cg = -1;
            #pragma unroll
            for (int r = 0; r < 4; ++r) {
                float v = fmaxf(acc2[mi][ni][r] + bc3[ni], 0.f);
                if (nd[r] != cg) {
                    if (cg >= 0) atomicAdd(agg + (size_t)cg * 128 + col, mv);
                    cg = nd[r]; mv = v;
                } else mv += v;
            }
            if (cg >= 0) atomicAdd(agg + (size_t)cg * 128 + col, mv);
        }
    }
}

// ---------------------------------------------------------------------------
// Fused counting sort, both keys (parent=dst, child=src) in single launches.
// hist/cur are [2*NBINS] (half 0 = dst, half 1 = src); part is [2*NPART];
// outputs sA/sB/sC are [2*NE] (child half offset by NE via cursor bias).
// deg(src) == hist[NBINS + n] (int) -- consumed directly by SrcUpd.
// ---------------------------------------------------------------------------
__global__ void hist2_kernel(const int* __restrict__ dstI, const int* __restrict__ srcI,
                             int* __restrict__ hist)
{
    int i = blockIdx.x * 256 + threadIdx.x;
    if (i < NE) atomicAdd(&hist[dstI[i]], 1);
    else if (i < 2 * NE) atomicAdd(&hist[NBINS + srcI[i - NE]], 1);
}
__global__ void chunk_sum(const int* __restrict__ h, int* __restrict__ part)
{
    __shared__ int sh[256];
    int t = threadIdx.x, b = blockIdx.x;       // b in [0, 2*NPART)
    sh[t] = h[b * 256 + t];
    __syncthreads();
    for (int o = 128; o > 0; o >>= 1) { if (t < o) sh[t] += sh[t + o]; __syncthreads(); }
    if (t == 0) part[b] = sh[0];
}
__global__ void scan_part2(int* part)          // 2 blocks; per-half exclusive scan
{
    __shared__ int sh[256];
    int t = threadIdx.x, b = blockIdx.x;
    int* p = part + b * NPART;
    sh[t] = (t < NPART) ? p[t] : 0;
    __syncthreads();
    for (int o = 1; o < 256; o <<= 1) {
        int x = (t >= o) ? sh[t - o] : 0;
        __syncthreads(); sh[t] += x; __syncthreads();
    }
    if (t < NPART) p[t] = (t ? sh[t - 1] : 0) + b * NE;   // child half biased by NE
}
__global__ void mk_cursor(const int* __restrict__ h, const int* __restrict__ part,
                          int* __restrict__ cur)
{
    __shared__ int sh[256];
    int t = threadIdx.x, b = blockIdx.x;       // b in [0, 2*NPART)
    int v = h[b * 256 + t];
    sh[t] = v;
    __syncthreads();
    for (int o = 1; o < 256; o <<= 1) {
        int x = (t >= o) ? sh[t - o] : 0;
        __syncthreads(); sh[t] += x; __syncthreads();
    }
    cur[b * 256 + t] = part[b] + sh[t] - v;
}
__global__ void sort_scatter2(const int* __restrict__ dstI, const int* __restrict__ srcI,
                              const int* __restrict__ at, int* __restrict__ cur,
                              int* __restrict__ oA, int* __restrict__ oB, int* __restrict__ oC)
{
    int i = blockIdx.x * 256 + threadIdx.x;
    if (i < NE) {
        int k = dstI[i];
        int p = atomicAdd(&cur[k], 1);
        oA[p] = k; oB[p] = srcI[i]; oC[p] = at[i];
    } else if (i < 2 * NE) {
        int e = i - NE;
        int k = srcI[e];
        int p = atomicAdd(&cur[NBINS + k], 1);   // cursor pre-biased by NE
        oA[p] = k; oB[p] = dstI[e]; oC[p] = at[e];
    }
}

// ---------------------------------------------------------------------------
// Mega weight packer: all 15 pack jobs in one launch (constexpr job table).
// ---------------------------------------------------------------------------
struct PackPtrs { const float* p[13]; };

__global__ void pack_all(PackPtrs pp, uint4* __restrict__ frag)
{
    int tid = blockIdx.x * 256 + threadIdx.x;
    if (tid >= 126976) return;
    constexpr int NJ = 15;
    const int   start[NJ] = {0,4096,6144,10240,14336,18432,22528,26624,28672,32768,34816,47104,51200,53248,61440};
    const int   fbase[NJ] = {0,4096,6144,6144,14336,14336,22528,26624,28672,32768,34816,47104,51200,53248,61440};
    const short wsel [NJ] = {0,1,2,2,3,3,4,5,6,7,8,9,10,11,12};
    const short ldt  [NJ] = {128,128,256,256,256,256,128,128,128,128,256,128,128,512,1024};
    const short rot  [NJ] = {0,0,0,128,0,128,0,0,0,0,0,0,0,0,0};
    const short cot  [NJ] = {0,0,0,-256,0,-256,0,0,0,0,0,0,0,0,0};
    const short nbst [NJ] = {0,0,0,2,0,2,0,0,0,0,0,0,0,0,0};
    const short kst  [NJ] = {8,4,4,4,4,4,8,4,8,4,12,8,4,4,16};
    int j = 0;
    for (int i = NJ - 1; i >= 1; --i) if (tid >= start[i]) { j = i; break; }
    int rem = tid - start[j];
    int KS = kst[j];
    int nbrel = rem / (KS * 512);
    int r1 = rem % (KS * 512);
    int ks = r1 >> 9;
    int r2 = r1 & 511;
    int nt = r2 >> 6, l = r2 & 63;
    int nb = nbst[j] + nbrel;
    int k  = ks * 32 + (l >> 4) * 8;
    int ld = ldt[j];
    int col = nb * 128 + nt * 16 + (l & 15) + cot[j];
    const float* W = pp.p[wsel[j]];
    U16x8 u;
    #pragma unroll
    for (int jj = 0; jj < 8; ++jj) u.s[jj] = f2b(W[(size_t)(rot[j] + k + jj) * ld + col]);
    frag[fbase[j] + ((size_t)(nb * KS + ks) * 8 + nt) * 64 + l] = u.u;
}

// ---------------------------------------------------------------------------
// Edge-type tables, fused: ea = enc(emb_edge) (LDS only), then
// T{p,c}[a][j] = ea[a] @ W{p,c}1[256:384][j] + b{p,c}1[j].
// ---------------------------------------------------------------------------
__global__ void enc_tab_kernel(const float* __restrict__ emb_edge,
                               const float* __restrict__ We1, const float* __restrict__ be1,
                               const float* __restrict__ We2, const float* __restrict__ be2,
                               const float* __restrict__ Wp1, const float* __restrict__ bp1,
                               const float* __restrict__ Wc1, const float* __restrict__ bc1,
                               float* __restrict__ Tp, float* __restrict__ Tc)
{
    __shared__ float h1[3][128];
    __shared__ float ea[3][128];
    const int t = threadIdx.x;   // 256
    if (t < 128) {
        for (int a = 0; a < 3; ++a) {
            float s = be1[t];
            for (int k = 0; k < 256; ++k) s = fmaf(emb_edge[a * 256 + k], We1[k * 128 + t], s);
            h1[a][t] = fmaxf(s, 0.f);
        }
    }
    __syncthreads();
    if (t < 128) {
        for (int a = 0; a < 3; ++a) {
            float s = be2[t];
            for (int k = 0; k < 128; ++k) s = fmaf(h1[a][k], We2[k * 128 + t], s);
            ea[a][t] = fmaxf(s, 0.f);
        }
    }
    __syncthreads();
    for (int a = 0; a < 3; ++a) {
        float sp = bp1[t], sc = bc1[t];
        for (int k = 0; k < 128; ++k) {
            float e = ea[a][k];
            sp = fmaf(e, Wp1[(size_t)(256 + k) * 256 + t], sp);
            sc = fmaf(e, Wc1[(size_t)(256 + k) * 256 + t], sc);
        }
        Tp[a * 256 + t] = sp;
        Tc[a * 256 + t] = sc;
    }
}

// ---------------------------------------------------------------------------
extern "C" void kernel_launch(void* const* d_in, const int* in_sizes, int n_in,
                              void* d_out, int out_size, void* d_ws, size_t ws_size,
                              hipStream_t stream)
{
    const int*   x          = (const int*)d_in[0];
    const int*   edge_index = (const int*)d_in[1];
    const int*   edge_attr  = (const int*)d_in[2];
    const int*   batch_vec  = (const int*)d_in[3];
    const float* emb_node   = (const float*)d_in[4];
    const float* Wn1 = (const float*)d_in[5];  const float* bn1 = (const float*)d_in[6];
    const float* Wn2 = (const float*)d_in[7];  const float* bn2 = (const float*)d_in[8];
    const float* emb_edge = (const float*)d_in[9];
    const float* We1 = (const float*)d_in[10]; const float* be1 = (const float*)d_in[11];
    const float* We2 = (const float*)d_in[12]; const float* be2 = (const float*)d_in[13];
    const float* Wp1 = (const float*)d_in[14]; const float* bp1 = (const float*)d_in[15];
    const float* Wp2 = (const float*)d_in[16]; const float* bp2 = (const float*)d_in[17];
    const float* Wp3 = (const float*)d_in[18]; const float* bp3 = (const float*)d_in[19];
    const float* Wc1 = (const float*)d_in[20]; const float* bc1 = (const float*)d_in[21];
    const float* Wc2 = (const float*)d_in[22]; const float* bc2 = (const float*)d_in[23];
    const float* Wc3 = (const float*)d_in[24]; const float* bc3 = (const float*)d_in[25];
    const float* Wf1 = (const float*)d_in[26]; const float* bf1 = (const float*)d_in[27];
    const float* Wf2 = (const float*)d_in[28]; const float* bf2 = (const float*)d_in[29];
    const float* Wf3 = (const float*)d_in[30]; const float* bf3 = (const float*)d_in[31];
    const float* Wo1 = (const float*)d_in[32]; const float* bo1 = (const float*)d_in[33];
    const float* Wo2 = (const float*)d_in[34]; const float* bo2 = (const float*)d_in[35];

    float* out = (float*)d_out;

    char* w = (char*)d_ws;
    auto alloc = [&](size_t bytes) { char* p = w; w += (bytes + 255) & ~(size_t)255; return p; };
    float* nodes   = (float*)alloc((size_t)NN * DD * 4);
    u16*   nodesbf = (u16*)  alloc((size_t)NN * DD * 2);
    float* fi      = (float*)alloc((size_t)NN * DD * 4);
    float* fo      = (float*)alloc((size_t)NN * DD * 4);   // contiguous after fi
    u16*   P       = (u16*)  alloc((size_t)NN * 512 * 2);
    u16*   h2      = (u16*)  alloc((size_t)NN * 384 * 2);
    float* Tp      = (float*)alloc(3 * 256 * 4);
    float* Tc      = (float*)alloc(3 * 256 * 4);
    uint4* frag    = (uint4*)alloc((size_t)126976 * 16);
    int* hist = (int*)alloc((size_t)2 * NBINS * 4);        // [dst | src]; src half = deg
    int* part = (int*)alloc((size_t)2 * NPART * 4);
    int* cur  = (int*)alloc((size_t)2 * NBINS * 4);
    int* sA   = (int*)alloc((size_t)2 * NE * 4);           // [parent | child]
    int* sB   = (int*)alloc((size_t)2 * NE * 4);
    int* sC   = (int*)alloc((size_t)2 * NE * 4);

    u16* He = h2;                      // [50k][128]
    u16* U1 = h2;                      // [50k][256]
    u16* U2 = h2 + (size_t)NN * 256;   // [50k][128]
    u16* Hout1 = P;                    // [50k][512]
    const int* degS = hist + NBINS;    // deg(src) as int

    uint4* Wn1f = frag;                // K256 N128
    uint4* Wn2f = Wn1f + 4096;         // K128 N128
    uint4* PWp  = Wn2f + 2048;         // K128 N512
    uint4* PWc  = PWp  + 8192;
    uint4* W2p  = PWc  + 8192;         // K256 N128
    uint4* W3p  = W2p  + 4096;         // K128 N128
    uint4* W2c  = W3p  + 2048;
    uint4* W3c  = W2c  + 4096;
    uint4* Wf1f = W3c  + 2048;         // K384 N256
    uint4* Wf2f = Wf1f + 12288;        // K256 N128
    uint4* Wf3f = Wf2f + 4096;         // K128 N128
    uint4* Wo1f = Wf3f + 2048;         // K128 N512
    uint4* Wo2f = Wo1f + 8192;         // K512 N1024

    const int* srcI = edge_index;
    const int* dstI = edge_index + NE;

    const int MB50 = (NN + 127) / 128;   // 391
    const int MBE  = (NE + 127) / 128;   // 1563

    // ---- prep (7 launches + 2 memsets) -------------------------------------
    (void)hipMemsetAsync(d_out, 0, (size_t)out_size * 4, stream);
    (void)hipMemsetAsync(hist, 0, (size_t)2 * NBINS * 4, stream);

    PackPtrs pp;
    pp.p[0]=Wn1; pp.p[1]=Wn2; pp.p[2]=Wp1; pp.p[3]=Wc1; pp.p[4]=Wp2; pp.p[5]=Wp3;
    pp.p[6]=Wc2; pp.p[7]=Wc3; pp.p[8]=Wf1; pp.p[9]=Wf2; pp.p[10]=Wf3; pp.p[11]=Wo1; pp.p[12]=Wo2;
    pack_all<<<(126976 + 255) / 256, 256, 0, stream>>>(pp, frag);

    enc_tab_kernel<<<1, 256, 0, stream>>>(emb_edge, We1, be1, We2, be2,
                                          Wp1, bp1, Wc1, bc1, Tp, Tc);

    hist2_kernel<<<(2 * NE + 255) / 256, 256, 0, stream>>>(dstI, srcI, hist);
    chunk_sum<<<2 * NPART, 256, 0, stream>>>(hist, part);
    scan_part2<<<2, 256, 0, stream>>>(part);
    mk_cursor<<<2 * NPART, 256, 0, stream>>>(hist, part, cur);
    sort_scatter2<<<(2 * NE + 255) / 256, 256, 0, stream>>>(dstI, srcI, edge_attr, cur, sA, sB, sC);

    // ---- node encoder ------------------------------------------------------
    gemm_k<256, 1, 0, true, SrcEnc><<<MB50, 256, 0, stream>>>(
        SrcEnc{emb_node, x}, Wn1f, bn1, EpiArgs{nullptr, He, nullptr, 128}, NN);
    expand_k<128, 1, 1, true, 128><<<dim3(MB50, 1), 256, 0, stream>>>(
        He, Wn2f, bn2, nodes, nodesbf, NN);

    // ---- message-passing iterations ---------------------------------------
    for (int it = 0; it < NITERS; ++it) {
        (void)hipMemsetAsync(fi, 0, (size_t)2 * NN * DD * 4, stream);  // fi + fo

        expand_k<128, 4, 0, false, 512><<<dim3(MB50, 4), 256, 0, stream>>>(
            nodesbf, PWp, nullptr, nullptr, P, NN);
        edge_fused<<<MBE, 256, 0, stream>>>(P, Tp, W2p, bp2, W3p, bp3,
                                            sA, sB, sC, fi);

        expand_k<128, 4, 0, false, 512><<<dim3(MB50, 4), 256, 0, stream>>>(
            nodesbf, PWc, nullptr, nullptr, P, NN);
        edge_fused<<<MBE, 256, 0, stream>>>(P, Tc, W2c, bc2, W3c, bc3,
                                            sA + NE, sB + NE, sC + NE, fo);

        gemm_k<384, 2, 0, true, SrcUpd><<<MB50 * 2, 256, 0, stream>>>(
            SrcUpd{nodes, fi, fo, degS}, Wf1f, bf1, EpiArgs{nullptr, U1, nullptr, 256}, NN);
        expand_k<256, 1, 0, true, 128><<<dim3(MB50, 1), 256, 0, stream>>>(
            U1, Wf2f, bf2, nullptr, U2, NN);
        expand_k<128, 1, 2, true, 128><<<dim3(MB50, 1), 256, 0, stream>>>(
            U2, Wf3f, bf3, nodes, nodesbf, NN);
    }

    // ---- output head + global max pool -------------------------------------
    expand_k<128, 4, 0, true, 512><<<dim3(MB50, 4), 256, 0, stream>>>(
        nodesbf, Wo1f, bo1, nullptr, Hout1, NN);
    gemm_k<512, 8, 3, true, SrcBf16><<<MB50 * 8, 256, 0, stream>>>(
        SrcBf16{Hout1, 512}, Wo2f, bo2, EpiArgs{out, nullptr, batch_vec, 1024}, NN);
}